// Round 6
// baseline (1101.490 us; speedup 1.0000x reference)
//
#include <hip/hip_runtime.h>

typedef _Float16 f16;
typedef __attribute__((ext_vector_type(8))) _Float16 half8;
typedef __attribute__((ext_vector_type(4))) _Float16 half4;
typedef __attribute__((ext_vector_type(4))) float f32x4;

__device__ inline f32x4 mfma16(half8 a, half8 b, f32x4 c) {
  return __builtin_amdgcn_mfma_f32_16x16x32_f16(a, b, c, 0, 0, 0);
}

// ---------------- weight prep ----------------
// GLU weights: Wt[l][r][tap*256+i] (f16), rows reordered so each 32-row group
// is 16 a-channels then 16 g-channels. One block per (l,r) row.
__global__ void prep_wtglu_kernel(const float* __restrict__ mel_w,
                                  const float* __restrict__ ph_w,
                                  f16* __restrict__ wt) {
  int bid = blockIdx.x;          // l*512 + r
  int l = bid >> 9, r = bid & 511;
  int tid = threadIdx.x;         // 0..255 = input channel i
  int n32 = r >> 5, j = r & 31;
  int ch = (j < 16) ? (n32 * 16 + j) : (256 + n32 * 16 + (j - 16));
  const float* src = ((l < 4) ? (mel_w + (size_t)l * 512 * 256 * 3)
                              : (ph_w + (size_t)(l - 4) * 512 * 256 * 3)) +
                     (size_t)ch * 768;
  f16* dst = wt + (size_t)bid * 768;
  float a0 = src[tid * 3], a1 = src[tid * 3 + 1], a2 = src[tid * 3 + 2];
  dst[tid] = (f16)a0;
  dst[256 + tid] = (f16)a1;
  dst[512 + tid] = (f16)a2;
}

// mel conv0 weights: Wt0[o][tap*96+i] (f16), channels padded 80->96 with zeros.
__global__ void prep_wt0_kernel(const float* __restrict__ w, f16* __restrict__ wt0) {
  int idx = blockIdx.x * 256 + threadIdx.x;
  const int total = 256 * 288;
  if (idx >= total) return;
  int o = idx / 288, k = idx % 288;
  int tap = k / 96, i = k % 96;
  wt0[idx] = (i < 80) ? (f16)w[((size_t)o * 80 + i) * 3 + tap] : (f16)0.f;
}

// ---------------- embedding (with blank prepend), f32 -> f16 ----------------
__global__ void embed_kernel(const int* __restrict__ phon, const float* __restrict__ emb,
                             f16* __restrict__ out) {
  int s = blockIdx.x, b = blockIdx.y;
  int lane = threadIdx.x;
  int tok = (s == 0) ? 0 : phon[b * 512 + (s - 1)];
  float4 f = *(const float4*)(emb + (size_t)tok * 256 + lane * 4);
  half4 h = {(f16)f.x, (f16)f.y, (f16)f.z, (f16)f.w};
  *(half4*)(out + ((size_t)b * 513 + s) * 256 + lane * 4) = h;
}

// ---------------- mel conv0 (K = 3 taps x 96 padded ch) ----------------
__global__ __launch_bounds__(256) void conv0_kernel(
    const float* __restrict__ mels, const f16* __restrict__ wt0,
    const float* __restrict__ bias, f16* __restrict__ out) {
  __shared__ f16 xs[66 * 104];
  __shared__ f16 ws[64 * 104];
  const int tid = threadIdx.x;
  const int b = blockIdx.z;
  const int t0 = blockIdx.x * 64;
  const int by = blockIdx.y;  // 0..3 (64 out-ch each)

  for (int idx = tid; idx < 66 * 24; idx += 256) {
    int r = idx / 24, v = idx % 24;
    int t = t0 - 1 + r;
    half4 h = {0.f, 0.f, 0.f, 0.f};
    if (t >= 0 && t < 2000 && v < 20) {
      float4 f = *(const float4*)(mels + ((size_t)b * 2000 + t) * 80 + v * 4);
      h[0] = (f16)f.x; h[1] = (f16)f.y; h[2] = (f16)f.z; h[3] = (f16)f.w;
    }
    *(half4*)(xs + r * 104 + v * 4) = h;
  }
  const int lane = tid & 63, wv = tid >> 6;
  const int wr = wv >> 1, wc = wv & 1;
  const int l15 = lane & 15, q = lane >> 4;
  f32x4 acc[2][2] = {};
  const f16* wrow = wt0 + (size_t)(by * 64) * 288;
  for (int tap = 0; tap < 3; ++tap) {
    __syncthreads();
    for (int idx = tid; idx < 64 * 12; idx += 256) {
      int r = idx / 12, v = idx % 12;
      *(half8*)(ws + r * 104 + v * 8) =
          *(const half8*)(wrow + (size_t)r * 288 + tap * 96 + v * 8);
    }
    __syncthreads();
#pragma unroll
    for (int s2 = 0; s2 < 3; ++s2) {
      int ch = s2 * 32 + q * 8;
      half8 a0 = *(const half8*)(xs + (32 * wr + l15 + tap) * 104 + ch);
      half8 a1 = *(const half8*)(xs + (32 * wr + 16 + l15 + tap) * 104 + ch);
      half8 b0 = *(const half8*)(ws + (32 * wc + l15) * 104 + ch);
      half8 b1 = *(const half8*)(ws + (32 * wc + 16 + l15) * 104 + ch);
      acc[0][0] = mfma16(a0, b0, acc[0][0]);
      acc[0][1] = mfma16(a0, b1, acc[0][1]);
      acc[1][0] = mfma16(a1, b0, acc[1][0]);
      acc[1][1] = mfma16(a1, b1, acc[1][1]);
    }
  }
#pragma unroll
  for (int rf = 0; rf < 2; ++rf)
#pragma unroll
    for (int cf = 0; cf < 2; ++cf) {
      int c = by * 64 + 32 * wc + 16 * cf + l15;
      float bb = bias[c];
#pragma unroll
      for (int r = 0; r < 4; ++r) {
        int t = t0 + 32 * wr + 16 * rf + 4 * q + r;
        if (t < 2000)
          out[((size_t)b * 2000 + t) * 256 + c] = (f16)(acc[rf][cf][r] + bb);
      }
    }
}

// ---------------- GLU v6: 128t x 128n block, BK=64 -------------------------
// X: v4-style reg-prefetch -> LDS (waitcnt lands at next iter's ds_write ->
// long hiding window). W: B-frags read DIRECT from global (per-ks W slice =
// 16KB, shared by 16 consecutive blocks -> L1-resident; same regime as
// flash's direct-global K). Halves per-ks LDS traffic (96KB -> 48KB/block)
// and shortens the ds_write->barrier->ds_read critical chain; frees wreg.
// v5's global_load_lds variant regressed (vmcnt(0) drain barrier after only
// ~160cy of MFMA -> HBM latency exposed every ks).
// y = conv(x_masked) + b; out = (a * sigmoid(g) + x_masked) * sqrt(0.5)
__global__ __launch_bounds__(256) void glu_kernel(
    const f16* __restrict__ x, const f16* __restrict__ wt,
    const float* __restrict__ bias, f16* __restrict__ out,
    const int* __restrict__ lens, int lenAdd, int T) {
  __shared__ f16 xs[128 * 72];
  const int tid = threadIdx.x;
  const int b = blockIdx.z;
  const int t0 = blockIdx.x * 128;
  const int by = blockIdx.y;  // 0..3 (128 reordered rows each)
  int thr = lens[b] + lenAdd;
  if (thr > T) thr = T;
  const size_t xbase = (size_t)b * T * 256;
  const int lane = tid & 63, wv = tid >> 6;
  const int wr = wv >> 1, wc = wv & 1;   // wave tile 64t x 64n
  const int l15 = lane & 15, q = lane >> 4;
  f32x4 acc[4][4] = {};
  const f16* wrow = wt + (size_t)(by * 128) * 768;
  const int r_st = tid >> 3, v_st = tid & 7;

  half8 xr[4];
  auto loadChunk = [&](int ks) {
    int tap = ks >> 2, cb = (ks & 3) * 64;
#pragma unroll
    for (int it = 0; it < 4; ++it) {
      int r = r_st + 32 * it;
      int trow = t0 + r + tap - 1;
      half8 val = {};
      if (trow >= 0 && trow < thr)
        val = *(const half8*)(x + xbase + (size_t)trow * 256 + cb + v_st * 8);
      xr[it] = val;
    }
  };
  loadChunk(0);

  const f16* wbase = wrow + (size_t)(wc * 64) * 768;  // this wave's B rows

  for (int ks = 0; ks < 12; ++ks) {
    __syncthreads();   // previous chunk's ds_reads done
#pragma unroll
    for (int it = 0; it < 4; ++it)
      *(half8*)(xs + (r_st + 32 * it) * 72 + v_st * 8) = xr[it];
    __syncthreads();   // LDS ready
    if (ks < 11) loadChunk(ks + 1);   // in flight during MFMA below

    half8 af[4][2];
#pragma unroll
    for (int mt = 0; mt < 4; ++mt)
#pragma unroll
      for (int kc = 0; kc < 2; ++kc)
        af[mt][kc] = *(const half8*)(xs + (wr * 64 + mt * 16 + l15) * 72 + kc * 32 + q * 8);
    __builtin_amdgcn_s_setprio(1);
#pragma unroll
    for (int nt = 0; nt < 4; ++nt) {
      const f16* wrp = wbase + (size_t)(nt * 16 + l15) * 768 + ks * 64;
      half8 b0 = *(const half8*)(wrp + q * 8);
      half8 b1 = *(const half8*)(wrp + 32 + q * 8);
#pragma unroll
      for (int mt = 0; mt < 4; ++mt) {
        acc[mt][nt] = mfma16(af[mt][0], b0, acc[mt][nt]);
        acc[mt][nt] = mfma16(af[mt][1], b1, acc[mt][nt]);
      }
    }
    __builtin_amdgcn_s_setprio(0);
  }

  // epilogue: nt pairs (0,1),(2,3) are (a,g) channel groups (rows reordered)
#pragma unroll
  for (int p = 0; p < 2; ++p) {
    int n32 = by * 4 + wc * 2 + p;
    int c = n32 * 16 + l15;
    float ba = bias[c], bg = bias[256 + c];
#pragma unroll
    for (int mt = 0; mt < 4; ++mt) {
#pragma unroll
      for (int rr = 0; rr < 4; ++rr) {
        int t = t0 + wr * 64 + mt * 16 + q * 4 + rr;
        if (t < T) {
          float a = acc[mt][2 * p][rr] + ba;
          float g = acc[mt][2 * p + 1][rr] + bg;
          float xm = (t < thr) ? (float)x[xbase + (size_t)t * 256 + c] : 0.f;
          float o = (a * (1.0f / (1.0f + __expf(-g))) + xm) * 0.70710678118f;
          out[xbase + (size_t)t * 256 + c] = (f16)o;
        }
      }
    }
  }
}

// ---------------- transpose ph_enc -> phT [b][256 d][576 s] (zeros padded) ----------------
__global__ __launch_bounds__(256) void transpose_kernel(const f16* __restrict__ ph,
                                                        f16* __restrict__ phT) {
  __shared__ f16 tile[64 * 72];
  const int tid = threadIdx.x;
  const int b = blockIdx.z, s0 = blockIdx.x * 64, d0 = blockIdx.y * 64;
#pragma unroll
  for (int it = 0; it < 2; ++it) {
    int idx = tid + it * 256;
    int r = idx >> 3, v = idx & 7;
    int s = s0 + r;
    half8 val = {};
    if (s < 513) val = *(const half8*)(ph + ((size_t)b * 513 + s) * 256 + d0 + v * 8);
    *(half8*)(tile + r * 72 + v * 8) = val;
  }
  __syncthreads();
#pragma unroll
  for (int it = 0; it < 2; ++it) {
    int idx = tid + it * 256;
    int r = idx >> 3, v = idx & 7;   // r = local d, v*8+j = local s
    half8 val;
#pragma unroll
    for (int j2 = 0; j2 < 8; ++j2) val[j2] = tile[(v * 8 + j2) * 72 + r];
    *(half8*)(phT + ((size_t)b * 256 + d0 + r) * 576 + s0 + v * 8) = val;
  }
}

// ---------------- squared norms (phoneme side; mel_sq cancels in softmax) ----------------
__global__ void sqnorm_kernel(const f16* __restrict__ x, float* __restrict__ sq, int nrows) {
  int row = blockIdx.x * 4 + (threadIdx.x >> 6);
  int lane = threadIdx.x & 63;
  if (row >= nrows) return;
  const f16* p = x + (size_t)row * 256;
  float v = 0.f;
  for (int i = lane; i < 256; i += 64) { float f = (float)p[i]; v += f * f; }
  for (int off = 32; off > 0; off >>= 1) v += __shfl_down(v, off);
  if (lane == 0) sq[row] = v;
}

// ---------------- fused dist+softmax+context + mel copy (flash-style) ----------------
// v7: r0's proven structure (V^T reg-prefetch -> LDS vt, 2 barriers/kt,
// K direct from global with 4 parallel sc chains) + XCD-bijective swizzle
// (4 batches/XCD -> ph+phT working set ~3.4MB L2-resident per XCD) +
// one-time phs preload + s_setprio(1) around MFMA clusters.
// scores(t,s) = 2*dot(mel_t, ph_s) - |ph_s|^2  (row-constant -|mel_t|^2 dropped).
// K reads for s in [513,576) hit in-workspace garbage but are masked pre-max.
__global__ __launch_bounds__(256) void flash_kernel(
    const f16* __restrict__ mel, const f16* __restrict__ ph,
    const f16* __restrict__ phT, const float* __restrict__ phsq,
    const int* __restrict__ plens, float* __restrict__ out) {
  __shared__ f16 vt[256 * 72];   // V^T tile [d][s-local]
  __shared__ f16 ps[4][16 * 72]; // per-wave P 16x64 (wave-private)
  __shared__ float phs[576];
  const int tid = threadIdx.x;
  // XCD swizzle (bijective): b = (lin>>8)*8 + (lin&7), tt = (lin>>3)&31.
  const int lin = blockIdx.x;
  const int b = ((lin >> 8) << 3) | (lin & 7);
  const int t0 = ((lin >> 3) & 31) * 64;
  const int lane = tid & 63, wv = tid >> 6;
  const int l15 = lane & 15, q = lane >> 4;
  const int plen = plens[b];

  for (int idx = tid; idx < 576; idx += 256)
    phs[idx] = (idx < 513) ? phsq[b * 513 + idx] : 0.f;

  // Q fragments in registers (wave's 16 rows)
  const int tq = t0 + 16 * wv + l15;
  half8 qf[8];
  {
    const f16* qrow = mel + ((size_t)b * 2000 + ((tq < 2000) ? tq : 0)) * 256;
#pragma unroll
    for (int c = 0; c < 8; ++c) qf[c] = *(const half8*)(qrow + c * 32 + q * 8);
    if (tq >= 2000) {
      half8 z = {};
#pragma unroll
      for (int c = 0; c < 8; ++c) qf[c] = z;
    }
  }
  // fused copymel: out[..., 0:256] = mel_enc (from qf, f16 -> f32)
  if (tq < 2000) {
    float* orow = out + ((size_t)b * 2000 + tq) * 512;
#pragma unroll
    for (int c = 0; c < 8; ++c) {
      half8 h = qf[c];
      float4 f0 = {(float)h[0], (float)h[1], (float)h[2], (float)h[3]};
      float4 f1 = {(float)h[4], (float)h[5], (float)h[6], (float)h[7]};
      *(float4*)(orow + c * 32 + q * 8) = f0;
      *(float4*)(orow + c * 32 + q * 8 + 4) = f1;
    }
  }

  half8 vreg[8];
  const int d_st = tid >> 3, v_st = tid & 7;
  auto loadV = [&](int kt) {
#pragma unroll
    for (int it = 0; it < 8; ++it) {
      int d = d_st + 32 * it;
      vreg[it] = *(const half8*)(phT + ((size_t)b * 256 + d) * 576 + kt * 64 + v_st * 8);
    }
  };
  loadV(0);

  float mr[4], lr[4];
#pragma unroll
  for (int r = 0; r < 4; ++r) { mr[r] = -3.0e38f; lr[r] = 0.f; }
  f32x4 acc[16] = {};
  f16* pw = ps[wv];

#pragma unroll 1
  for (int kt = 0; kt < 9; ++kt) {
    const int s0 = kt * 64;
    __syncthreads();  // prev iter's PV reads of vt done (kt=0: phs ready too)
#pragma unroll
    for (int it = 0; it < 8; ++it)
      *(half8*)(vt + (d_st + 32 * it) * 72 + v_st * 8) = vreg[it];
    __syncthreads();  // vt ready
    if (kt < 8) loadV(kt + 1);  // in flight during compute

    // QK^T: B-frags direct from global (identical across waves -> L1 hits)
    const f16* krow[4];
#pragma unroll
    for (int cf = 0; cf < 4; ++cf)
      krow[cf] = ph + ((size_t)b * 513 + (s0 + cf * 16 + l15)) * 256 + q * 8;
    f32x4 sc[4] = {};
    __builtin_amdgcn_s_setprio(1);
#pragma unroll
    for (int c = 0; c < 8; ++c) {
#pragma unroll
      for (int cf = 0; cf < 4; ++cf) {
        half8 bf = *(const half8*)(krow[cf] + c * 32);
        sc[cf] = mfma16(qf[c], bf, sc[cf]);
      }
    }
    __builtin_amdgcn_s_setprio(0);
    // score epilogue + online softmax (reduce across 16-lane quads)
    float p[4][4];
    float rmax[4] = {-3.0e38f, -3.0e38f, -3.0e38f, -3.0e38f};
#pragma unroll
    for (int cf = 0; cf < 4; ++cf) {
      int sloc = cf * 16 + l15;
      int s = s0 + sloc;
      bool msk = (s > plen) || (s >= 513);
      float p2 = phs[s0 + sloc];
#pragma unroll
      for (int r = 0; r < 4; ++r) {
        float v = 2.0f * sc[cf][r] - p2;
        if (msk) v = -1.0e9f;
        p[cf][r] = v;
        rmax[r] = fmaxf(rmax[r], v);
      }
    }
#pragma unroll
    for (int r = 0; r < 4; ++r)
#pragma unroll
      for (int off = 1; off < 16; off <<= 1)
        rmax[r] = fmaxf(rmax[r], __shfl_xor(rmax[r], off));
    float alpha[4];
#pragma unroll
    for (int r = 0; r < 4; ++r) {
      float mn = fmaxf(mr[r], rmax[r]);
      alpha[r] = __expf(mr[r] - mn);
      mr[r] = mn;
      float rs = 0.f;
#pragma unroll
      for (int cf = 0; cf < 4; ++cf) {
        float e = __expf(p[cf][r] - mn);
        p[cf][r] = e;
        rs += e;
      }
#pragma unroll
      for (int off = 1; off < 16; off <<= 1) rs += __shfl_xor(rs, off);
      lr[r] = lr[r] * alpha[r] + rs;
    }
#pragma unroll
    for (int dt = 0; dt < 16; ++dt)
#pragma unroll
      for (int r = 0; r < 4; ++r) acc[dt][r] *= alpha[r];
    // P to wave-private LDS (C-layout), read back in A-layout (no barrier:
    // wave-private region, lgkmcnt orders the ds ops within the wave)
#pragma unroll
    for (int cf = 0; cf < 4; ++cf)
#pragma unroll
      for (int r = 0; r < 4; ++r)
        pw[(q * 4 + r) * 72 + cf * 16 + l15] = (f16)p[cf][r];
    // PV: 16 t-rows x 256 d-cols, K = 64 (2 chunks), V from LDS
#pragma unroll
    for (int kc = 0; kc < 2; ++kc) {
      half8 pa = *(const half8*)(pw + l15 * 72 + kc * 32 + q * 8);
      __builtin_amdgcn_s_setprio(1);
#pragma unroll
      for (int dt = 0; dt < 16; ++dt) {
        half8 vb = *(const half8*)(vt + (dt * 16 + l15) * 72 + kc * 32 + q * 8);
        acc[dt] = mfma16(pa, vb, acc[dt]);
      }
      __builtin_amdgcn_s_setprio(0);
    }
  }
  float inv[4];
#pragma unroll
  for (int r = 0; r < 4; ++r) inv[r] = 1.0f / lr[r];
#pragma unroll
  for (int dt = 0; dt < 16; ++dt)
#pragma unroll
    for (int r = 0; r < 4; ++r) {
      int t = t0 + 16 * wv + q * 4 + r;
      if (t < 2000) {
        int d = dt * 16 + l15;
        out[((size_t)b * 2000 + t) * 512 + 256 + d] = acc[dt][r] * inv[r];
      }
    }
}

extern "C" void kernel_launch(void* const* d_in, const int* in_sizes, int n_in,
                              void* d_out, int out_size, void* d_ws, size_t ws_size,
                              hipStream_t stream) {
  (void)in_sizes; (void)n_in; (void)out_size; (void)ws_size;
  const float* mels       = (const float*)d_in[0];
  const int*   phonemes   = (const int*)d_in[1];
  const int*   mel_lens   = (const int*)d_in[2];
  const int*   ph_lens    = (const int*)d_in[3];
  const float* embedding  = (const float*)d_in[4];
  const float* mel_conv_w = (const float*)d_in[5];
  const float* mel_conv_b = (const float*)d_in[6];
  const float* ph_w       = (const float*)d_in[7];
  const float* ph_b       = (const float*)d_in[8];
  const float* mel_w      = (const float*)d_in[9];
  const float* mel_b      = (const float*)d_in[10];
  float* out = (float*)d_out;

  char* wsp = (char*)d_ws;
  size_t off = 0;
  auto alloc = [&](size_t bytes) -> void* {
    void* p = wsp + off;
    off = (off + bytes + 255) & ~(size_t)255;
    return p;
  };
  // NOTE: p0 must NOT be the last allocation — flash reads up to 63 rows past
  // its end (masked columns). m0 follows it -> in-workspace, safe. GLU also
  // reads 1 row before/after its x buffer (taps) -> in-workspace, masked.
  f16* wtg    = (f16*)alloc(8ull * 512 * 768 * 2);
  f16* wt0    = (f16*)alloc(256ull * 288 * 2);
  float* phsq = (float*)alloc(16416ull * 4);
  f16* p0     = (f16*)alloc(32ull * 513 * 256 * 2);
  f16* m0     = (f16*)alloc(32ull * 2000 * 256 * 2);
  f16* m1     = (f16*)alloc(32ull * 2000 * 256 * 2);
  f16* p1  = m1;        // ph ping buffer (mel ping is dead by then)
  f16* phT = m1;        // 9.4 MB <= 32.8 MB, used after ph GLUs done

  prep_wtglu_kernel<<<4096, 256, 0, stream>>>(mel_w, ph_w, wtg);
  prep_wt0_kernel<<<288, 256, 0, stream>>>(mel_conv_w, wt0);
  embed_kernel<<<dim3(513, 32), 64, 0, stream>>>(phonemes, embedding, p0);
  conv0_kernel<<<dim3(32, 4, 32), 256, 0, stream>>>(mels, wt0, mel_conv_b, m0);

  const size_t WL = 512ull * 768;
  // mel encoder: 4 GLU blocks (mask: t >= mel_lens[b])
  glu_kernel<<<dim3(16, 4, 32), 256, 0, stream>>>(m0, wtg + 0 * WL, mel_b + 0 * 512, m1, mel_lens, 0, 2000);
  glu_kernel<<<dim3(16, 4, 32), 256, 0, stream>>>(m1, wtg + 1 * WL, mel_b + 1 * 512, m0, mel_lens, 0, 2000);
  glu_kernel<<<dim3(16, 4, 32), 256, 0, stream>>>(m0, wtg + 2 * WL, mel_b + 2 * 512, m1, mel_lens, 0, 2000);
  glu_kernel<<<dim3(16, 4, 32), 256, 0, stream>>>(m1, wtg + 3 * WL, mel_b + 3 * 512, m0, mel_lens, 0, 2000);
  // phoneme encoder: 4 GLU blocks (mask: s > phoneme_lens[b])
  glu_kernel<<<dim3(5, 4, 32), 256, 0, stream>>>(p0, wtg + 4 * WL, ph_b + 0 * 512, p1, ph_lens, 1, 513);
  glu_kernel<<<dim3(5, 4, 32), 256, 0, stream>>>(p1, wtg + 5 * WL, ph_b + 1 * 512, p0, ph_lens, 1, 513);
  glu_kernel<<<dim3(5, 4, 32), 256, 0, stream>>>(p0, wtg + 6 * WL, ph_b + 2 * 512, p1, ph_lens, 1, 513);
  glu_kernel<<<dim3(5, 4, 32), 256, 0, stream>>>(p1, wtg + 7 * WL, ph_b + 3 * 512, p0, ph_lens, 1, 513);

  transpose_kernel<<<dim3(9, 4, 32), 256, 0, stream>>>(p0, phT);
  sqnorm_kernel<<<4104, 256, 0, stream>>>(p0, phsq, 16416);
  flash_kernel<<<dim3(1024), 256, 0, stream>>>(m0, p0, phT, phsq, ph_lens, out);
}

// Round 7
// 774.639 us; speedup vs baseline: 1.4219x; 1.4219x over previous
//
#include <hip/hip_runtime.h>

typedef _Float16 f16;
typedef __attribute__((ext_vector_type(8))) _Float16 half8;
typedef __attribute__((ext_vector_type(4))) _Float16 half4;
typedef __attribute__((ext_vector_type(4))) float f32x4;

__device__ inline f32x4 mfma16(half8 a, half8 b, f32x4 c) {
  return __builtin_amdgcn_mfma_f32_16x16x32_f16(a, b, c, 0, 0, 0);
}

// ---------------- weight prep ----------------
// GLU weights: Wt[l][r][tap*256+i] (f16), rows reordered so each 32-row group
// is 16 a-channels then 16 g-channels. One block per (l,r) row.
__global__ void prep_wtglu_kernel(const float* __restrict__ mel_w,
                                  const float* __restrict__ ph_w,
                                  f16* __restrict__ wt) {
  int bid = blockIdx.x;          // l*512 + r
  int l = bid >> 9, r = bid & 511;
  int tid = threadIdx.x;         // 0..255 = input channel i
  int n32 = r >> 5, j = r & 31;
  int ch = (j < 16) ? (n32 * 16 + j) : (256 + n32 * 16 + (j - 16));
  const float* src = ((l < 4) ? (mel_w + (size_t)l * 512 * 256 * 3)
                              : (ph_w + (size_t)(l - 4) * 512 * 256 * 3)) +
                     (size_t)ch * 768;
  f16* dst = wt + (size_t)bid * 768;
  float a0 = src[tid * 3], a1 = src[tid * 3 + 1], a2 = src[tid * 3 + 2];
  dst[tid] = (f16)a0;
  dst[256 + tid] = (f16)a1;
  dst[512 + tid] = (f16)a2;
}

// mel conv0 weights: Wt0[o][tap*96+i] (f16), channels padded 80->96 with zeros.
__global__ void prep_wt0_kernel(const float* __restrict__ w, f16* __restrict__ wt0) {
  int idx = blockIdx.x * 256 + threadIdx.x;
  const int total = 256 * 288;
  if (idx >= total) return;
  int o = idx / 288, k = idx % 288;
  int tap = k / 96, i = k % 96;
  wt0[idx] = (i < 80) ? (f16)w[((size_t)o * 80 + i) * 3 + tap] : (f16)0.f;
}

// ---------------- embedding (with blank prepend), f32 -> f16 ----------------
__global__ void embed_kernel(const int* __restrict__ phon, const float* __restrict__ emb,
                             f16* __restrict__ out) {
  int s = blockIdx.x, b = blockIdx.y;
  int lane = threadIdx.x;
  int tok = (s == 0) ? 0 : phon[b * 512 + (s - 1)];
  float4 f = *(const float4*)(emb + (size_t)tok * 256 + lane * 4);
  half4 h = {(f16)f.x, (f16)f.y, (f16)f.z, (f16)f.w};
  *(half4*)(out + ((size_t)b * 513 + s) * 256 + lane * 4) = h;
}

// ---------------- mel conv0 (K = 3 taps x 96 padded ch) ----------------
__global__ __launch_bounds__(256) void conv0_kernel(
    const float* __restrict__ mels, const f16* __restrict__ wt0,
    const float* __restrict__ bias, f16* __restrict__ out) {
  __shared__ f16 xs[66 * 104];
  __shared__ f16 ws[64 * 104];
  const int tid = threadIdx.x;
  const int b = blockIdx.z;
  const int t0 = blockIdx.x * 64;
  const int by = blockIdx.y;  // 0..3 (64 out-ch each)

  for (int idx = tid; idx < 66 * 24; idx += 256) {
    int r = idx / 24, v = idx % 24;
    int t = t0 - 1 + r;
    half4 h = {0.f, 0.f, 0.f, 0.f};
    if (t >= 0 && t < 2000 && v < 20) {
      float4 f = *(const float4*)(mels + ((size_t)b * 2000 + t) * 80 + v * 4);
      h[0] = (f16)f.x; h[1] = (f16)f.y; h[2] = (f16)f.z; h[3] = (f16)f.w;
    }
    *(half4*)(xs + r * 104 + v * 4) = h;
  }
  const int lane = tid & 63, wv = tid >> 6;
  const int wr = wv >> 1, wc = wv & 1;
  const int l15 = lane & 15, q = lane >> 4;
  f32x4 acc[2][2] = {};
  const f16* wrow = wt0 + (size_t)(by * 64) * 288;
  for (int tap = 0; tap < 3; ++tap) {
    __syncthreads();
    for (int idx = tid; idx < 64 * 12; idx += 256) {
      int r = idx / 12, v = idx % 12;
      *(half8*)(ws + r * 104 + v * 8) =
          *(const half8*)(wrow + (size_t)r * 288 + tap * 96 + v * 8);
    }
    __syncthreads();
#pragma unroll
    for (int s2 = 0; s2 < 3; ++s2) {
      int ch = s2 * 32 + q * 8;
      half8 a0 = *(const half8*)(xs + (32 * wr + l15 + tap) * 104 + ch);
      half8 a1 = *(const half8*)(xs + (32 * wr + 16 + l15 + tap) * 104 + ch);
      half8 b0 = *(const half8*)(ws + (32 * wc + l15) * 104 + ch);
      half8 b1 = *(const half8*)(ws + (32 * wc + 16 + l15) * 104 + ch);
      acc[0][0] = mfma16(a0, b0, acc[0][0]);
      acc[0][1] = mfma16(a0, b1, acc[0][1]);
      acc[1][0] = mfma16(a1, b0, acc[1][0]);
      acc[1][1] = mfma16(a1, b1, acc[1][1]);
    }
  }
#pragma unroll
  for (int rf = 0; rf < 2; ++rf)
#pragma unroll
    for (int cf = 0; cf < 2; ++cf) {
      int c = by * 64 + 32 * wc + 16 * cf + l15;
      float bb = bias[c];
#pragma unroll
      for (int r = 0; r < 4; ++r) {
        int t = t0 + 32 * wr + 16 * rf + 4 * q + r;
        if (t < 2000)
          out[((size_t)b * 2000 + t) * 256 + c] = (f16)(acc[rf][cf][r] + bb);
      }
    }
}

// ---------------- GLU v7: v4 structure + masked-block early-out -------------
// v4 (proven best): 128t x 128n block, BK=64, reg-prefetch dbuf for X and W.
// Early-out: if t0 > thr, every conv input row (incl. taps) is masked-zero ->
// y = bias -> out = bias_a*sigmoid(bias_g)*sqrt(.5), block-uniform per channel.
// ~45% of mel blocks / ~40% of ph blocks skip the whole MFMA pipeline.
// Branch is block-uniform (t0, thr) -> barrier-safe.
// y = conv(x_masked) + b; out = (a * sigmoid(g) + x_masked) * sqrt(0.5)
__global__ __launch_bounds__(256) void glu_kernel(
    const f16* __restrict__ x, const f16* __restrict__ wt,
    const float* __restrict__ bias, f16* __restrict__ out,
    const int* __restrict__ lens, int lenAdd, int T) {
  __shared__ f16 xs[128 * 72];
  __shared__ f16 ws2[128 * 72];
  const int tid = threadIdx.x;
  const int b = blockIdx.z;
  const int t0 = blockIdx.x * 128;
  const int by = blockIdx.y;  // 0..3 (128 reordered rows each)
  int thr = lens[b] + lenAdd;
  if (thr > T) thr = T;
  const size_t xbase = (size_t)b * T * 256;
  const int lane = tid & 63, wv = tid >> 6;
  const int wr = wv >> 1, wc = wv & 1;   // wave tile 64t x 64n
  const int l15 = lane & 15, q = lane >> 4;

  if (t0 > thr) {
    // all conv inputs for this block are masked-zero -> constant output
#pragma unroll
    for (int p = 0; p < 2; ++p) {
      int n32 = by * 4 + wc * 2 + p;
      int c = n32 * 16 + l15;
      float ba = bias[c], bg = bias[256 + c];
      f16 o = (f16)((ba * (1.0f / (1.0f + __expf(-bg)))) * 0.70710678118f);
#pragma unroll
      for (int mt = 0; mt < 4; ++mt)
#pragma unroll
        for (int rr = 0; rr < 4; ++rr) {
          int t = t0 + wr * 64 + mt * 16 + q * 4 + rr;
          if (t < T) out[xbase + (size_t)t * 256 + c] = o;
        }
    }
    return;
  }

  f32x4 acc[4][4] = {};
  const f16* wrow = wt + (size_t)(by * 128) * 768;
  const int r_st = tid >> 3, v_st = tid & 7;

  half8 xr[4], wreg[4];
  auto loadChunk = [&](int ks) {
    int tap = ks >> 2, cb = (ks & 3) * 64;
#pragma unroll
    for (int it = 0; it < 4; ++it) {
      int r = r_st + 32 * it;
      int trow = t0 + r + tap - 1;
      half8 val = {};
      if (trow >= 0 && trow < thr)
        val = *(const half8*)(x + xbase + (size_t)trow * 256 + cb + v_st * 8);
      xr[it] = val;
      wreg[it] = *(const half8*)(wrow + (size_t)r * 768 + ks * 64 + v_st * 8);
    }
  };
  loadChunk(0);

  for (int ks = 0; ks < 12; ++ks) {
    __syncthreads();   // previous chunk's MFMA reads done
#pragma unroll
    for (int it = 0; it < 4; ++it) {
      int r = r_st + 32 * it;
      *(half8*)(xs + r * 72 + v_st * 8) = xr[it];
      *(half8*)(ws2 + r * 72 + v_st * 8) = wreg[it];
    }
    __syncthreads();   // LDS ready
    if (ks < 11) loadChunk(ks + 1);   // in flight during MFMA below

    half8 af[4][2];
#pragma unroll
    for (int mt = 0; mt < 4; ++mt)
#pragma unroll
      for (int kc = 0; kc < 2; ++kc)
        af[mt][kc] = *(const half8*)(xs + (wr * 64 + mt * 16 + l15) * 72 + kc * 32 + q * 8);
#pragma unroll
    for (int nt = 0; nt < 4; ++nt) {
      half8 b0 = *(const half8*)(ws2 + (wc * 64 + nt * 16 + l15) * 72 + q * 8);
      half8 b1 = *(const half8*)(ws2 + (wc * 64 + nt * 16 + l15) * 72 + 32 + q * 8);
#pragma unroll
      for (int mt = 0; mt < 4; ++mt) {
        acc[mt][nt] = mfma16(af[mt][0], b0, acc[mt][nt]);
        acc[mt][nt] = mfma16(af[mt][1], b1, acc[mt][nt]);
      }
    }
  }

  // epilogue: nt pairs (0,1),(2,3) are (a,g) channel groups (rows reordered)
#pragma unroll
  for (int p = 0; p < 2; ++p) {
    int n32 = by * 4 + wc * 2 + p;
    int c = n32 * 16 + l15;
    float ba = bias[c], bg = bias[256 + c];
#pragma unroll
    for (int mt = 0; mt < 4; ++mt) {
#pragma unroll
      for (int rr = 0; rr < 4; ++rr) {
        int t = t0 + wr * 64 + mt * 16 + q * 4 + rr;
        if (t < T) {
          float a = acc[mt][2 * p][rr] + ba;
          float g = acc[mt][2 * p + 1][rr] + bg;
          float xm = (t < thr) ? (float)x[xbase + (size_t)t * 256 + c] : 0.f;
          float o = (a * (1.0f / (1.0f + __expf(-g))) + xm) * 0.70710678118f;
          out[xbase + (size_t)t * 256 + c] = (f16)o;
        }
      }
    }
  }
}

// ---------------- transpose ph_enc -> phT [b][256 d][576 s] (zeros padded) ----------------
__global__ __launch_bounds__(256) void transpose_kernel(const f16* __restrict__ ph,
                                                        f16* __restrict__ phT) {
  __shared__ f16 tile[64 * 72];
  const int tid = threadIdx.x;
  const int b = blockIdx.z, s0 = blockIdx.x * 64, d0 = blockIdx.y * 64;
#pragma unroll
  for (int it = 0; it < 2; ++it) {
    int idx = tid + it * 256;
    int r = idx >> 3, v = idx & 7;
    int s = s0 + r;
    half8 val = {};
    if (s < 513) val = *(const half8*)(ph + ((size_t)b * 513 + s) * 256 + d0 + v * 8);
    *(half8*)(tile + r * 72 + v * 8) = val;
  }
  __syncthreads();
#pragma unroll
  for (int it = 0; it < 2; ++it) {
    int idx = tid + it * 256;
    int r = idx >> 3, v = idx & 7;   // r = local d, v*8+j = local s
    half8 val;
#pragma unroll
    for (int j2 = 0; j2 < 8; ++j2) val[j2] = tile[(v * 8 + j2) * 72 + r];
    *(half8*)(phT + ((size_t)b * 256 + d0 + r) * 576 + s0 + v * 8) = val;
  }
}

// ---------------- squared norms (phoneme side; mel_sq cancels in softmax) ----------------
__global__ void sqnorm_kernel(const f16* __restrict__ x, float* __restrict__ sq, int nrows) {
  int row = blockIdx.x * 4 + (threadIdx.x >> 6);
  int lane = threadIdx.x & 63;
  if (row >= nrows) return;
  const f16* p = x + (size_t)row * 256;
  float v = 0.f;
  for (int i = lane; i < 256; i += 64) { float f = (float)p[i]; v += f * f; }
  for (int off = 32; off > 0; off >>= 1) v += __shfl_down(v, off);
  if (lane == 0) sq[row] = v;
}

// ---------------- fused dist+softmax+context + mel copy (flash-style) ----------------
// v7: r0's proven structure (V^T reg-prefetch -> LDS vt, 2 barriers/kt,
// K direct from global with 4 parallel sc chains) + XCD-bijective swizzle
// (4 batches/XCD -> ph+phT working set ~3.4MB L2-resident per XCD) +
// one-time phs preload + s_setprio(1) around MFMA clusters.
// scores(t,s) = 2*dot(mel_t, ph_s) - |ph_s|^2  (row-constant -|mel_t|^2 dropped).
// K reads for s in [513,576) hit in-workspace garbage but are masked pre-max.
__global__ __launch_bounds__(256) void flash_kernel(
    const f16* __restrict__ mel, const f16* __restrict__ ph,
    const f16* __restrict__ phT, const float* __restrict__ phsq,
    const int* __restrict__ plens, float* __restrict__ out) {
  __shared__ f16 vt[256 * 72];   // V^T tile [d][s-local]
  __shared__ f16 ps[4][16 * 72]; // per-wave P 16x64 (wave-private)
  __shared__ float phs[576];
  const int tid = threadIdx.x;
  // XCD swizzle (bijective): b = (lin>>8)*8 + (lin&7), tt = (lin>>3)&31.
  const int lin = blockIdx.x;
  const int b = ((lin >> 8) << 3) | (lin & 7);
  const int t0 = ((lin >> 3) & 31) * 64;
  const int lane = tid & 63, wv = tid >> 6;
  const int l15 = lane & 15, q = lane >> 4;
  const int plen = plens[b];

  for (int idx = tid; idx < 576; idx += 256)
    phs[idx] = (idx < 513) ? phsq[b * 513 + idx] : 0.f;

  // Q fragments in registers (wave's 16 rows)
  const int tq = t0 + 16 * wv + l15;
  half8 qf[8];
  {
    const f16* qrow = mel + ((size_t)b * 2000 + ((tq < 2000) ? tq : 0)) * 256;
#pragma unroll
    for (int c = 0; c < 8; ++c) qf[c] = *(const half8*)(qrow + c * 32 + q * 8);
    if (tq >= 2000) {
      half8 z = {};
#pragma unroll
      for (int c = 0; c < 8; ++c) qf[c] = z;
    }
  }
  // fused copymel: out[..., 0:256] = mel_enc (from qf, f16 -> f32)
  if (tq < 2000) {
    float* orow = out + ((size_t)b * 2000 + tq) * 512;
#pragma unroll
    for (int c = 0; c < 8; ++c) {
      half8 h = qf[c];
      float4 f0 = {(float)h[0], (float)h[1], (float)h[2], (float)h[3]};
      float4 f1 = {(float)h[4], (float)h[5], (float)h[6], (float)h[7]};
      *(float4*)(orow + c * 32 + q * 8) = f0;
      *(float4*)(orow + c * 32 + q * 8 + 4) = f1;
    }
  }

  half8 vreg[8];
  const int d_st = tid >> 3, v_st = tid & 7;
  auto loadV = [&](int kt) {
#pragma unroll
    for (int it = 0; it < 8; ++it) {
      int d = d_st + 32 * it;
      vreg[it] = *(const half8*)(phT + ((size_t)b * 256 + d) * 576 + kt * 64 + v_st * 8);
    }
  };
  loadV(0);

  float mr[4], lr[4];
#pragma unroll
  for (int r = 0; r < 4; ++r) { mr[r] = -3.0e38f; lr[r] = 0.f; }
  f32x4 acc[16] = {};
  f16* pw = ps[wv];

#pragma unroll 1
  for (int kt = 0; kt < 9; ++kt) {
    const int s0 = kt * 64;
    __syncthreads();  // prev iter's PV reads of vt done (kt=0: phs ready too)
#pragma unroll
    for (int it = 0; it < 8; ++it)
      *(half8*)(vt + (d_st + 32 * it) * 72 + v_st * 8) = vreg[it];
    __syncthreads();  // vt ready
    if (kt < 8) loadV(kt + 1);  // in flight during compute

    // QK^T: B-frags direct from global (identical across waves -> L1 hits)
    const f16* krow[4];
#pragma unroll
    for (int cf = 0; cf < 4; ++cf)
      krow[cf] = ph + ((size_t)b * 513 + (s0 + cf * 16 + l15)) * 256 + q * 8;
    f32x4 sc[4] = {};
    __builtin_amdgcn_s_setprio(1);
#pragma unroll
    for (int c = 0; c < 8; ++c) {
#pragma unroll
      for (int cf = 0; cf < 4; ++cf) {
        half8 bf = *(const half8*)(krow[cf] + c * 32);
        sc[cf] = mfma16(qf[c], bf, sc[cf]);
      }
    }
    __builtin_amdgcn_s_setprio(0);
    // score epilogue + online softmax (reduce across 16-lane quads)
    float p[4][4];
    float rmax[4] = {-3.0e38f, -3.0e38f, -3.0e38f, -3.0e38f};
#pragma unroll
    for (int cf = 0; cf < 4; ++cf) {
      int sloc = cf * 16 + l15;
      int s = s0 + sloc;
      bool msk = (s > plen) || (s >= 513);
      float p2 = phs[s0 + sloc];
#pragma unroll
      for (int r = 0; r < 4; ++r) {
        float v = 2.0f * sc[cf][r] - p2;
        if (msk) v = -1.0e9f;
        p[cf][r] = v;
        rmax[r] = fmaxf(rmax[r], v);
      }
    }
#pragma unroll
    for (int r = 0; r < 4; ++r)
#pragma unroll
      for (int off = 1; off < 16; off <<= 1)
        rmax[r] = fmaxf(rmax[r], __shfl_xor(rmax[r], off));
    float alpha[4];
#pragma unroll
    for (int r = 0; r < 4; ++r) {
      float mn = fmaxf(mr[r], rmax[r]);
      alpha[r] = __expf(mr[r] - mn);
      mr[r] = mn;
      float rs = 0.f;
#pragma unroll
      for (int cf = 0; cf < 4; ++cf) {
        float e = __expf(p[cf][r] - mn);
        p[cf][r] = e;
        rs += e;
      }
#pragma unroll
      for (int off = 1; off < 16; off <<= 1) rs += __shfl_xor(rs, off);
      lr[r] = lr[r] * alpha[r] + rs;
    }
#pragma unroll
    for (int dt = 0; dt < 16; ++dt)
#pragma unroll
      for (int r = 0; r < 4; ++r) acc[dt][r] *= alpha[r];
    // P to wave-private LDS (C-layout), read back in A-layout (no barrier:
    // wave-private region, lgkmcnt orders the ds ops within the wave)
#pragma unroll
    for (int cf = 0; cf < 4; ++cf)
#pragma unroll
      for (int r = 0; r < 4; ++r)
        pw[(q * 4 + r) * 72 + cf * 16 + l15] = (f16)p[cf][r];
    // PV: 16 t-rows x 256 d-cols, K = 64 (2 chunks), V from LDS
#pragma unroll
    for (int kc = 0; kc < 2; ++kc) {
      half8 pa = *(const half8*)(pw + l15 * 72 + kc * 32 + q * 8);
      __builtin_amdgcn_s_setprio(1);
#pragma unroll
      for (int dt = 0; dt < 16; ++dt) {
        half8 vb = *(const half8*)(vt + (dt * 16 + l15) * 72 + kc * 32 + q * 8);
        acc[dt] = mfma16(pa, vb, acc[dt]);
      }
      __builtin_amdgcn_s_setprio(0);
    }
  }
  float inv[4];
#pragma unroll
  for (int r = 0; r < 4; ++r) inv[r] = 1.0f / lr[r];
#pragma unroll
  for (int dt = 0; dt < 16; ++dt)
#pragma unroll
    for (int r = 0; r < 4; ++r) {
      int t = t0 + 16 * wv + q * 4 + r;
      if (t < 2000) {
        int d = dt * 16 + l15;
        out[((size_t)b * 2000 + t) * 512 + 256 + d] = acc[dt][r] * inv[r];
      }
    }
}

extern "C" void kernel_launch(void* const* d_in, const int* in_sizes, int n_in,
                              void* d_out, int out_size, void* d_ws, size_t ws_size,
                              hipStream_t stream) {
  (void)in_sizes; (void)n_in; (void)out_size; (void)ws_size;
  const float* mels       = (const float*)d_in[0];
  const int*   phonemes   = (const int*)d_in[1];
  const int*   mel_lens   = (const int*)d_in[2];
  const int*   ph_lens    = (const int*)d_in[3];
  const float* embedding  = (const float*)d_in[4];
  const float* mel_conv_w = (const float*)d_in[5];
  const float* mel_conv_b = (const float*)d_in[6];
  const float* ph_w       = (const float*)d_in[7];
  const float* ph_b       = (const float*)d_in[8];
  const float* mel_w      = (const float*)d_in[9];
  const float* mel_b      = (const float*)d_in[10];
  float* out = (float*)d_out;

  char* wsp = (char*)d_ws;
  size_t off = 0;
  auto alloc = [&](size_t bytes) -> void* {
    void* p = wsp + off;
    off = (off + bytes + 255) & ~(size_t)255;
    return p;
  };
  // NOTE: p0 must NOT be the last allocation — flash reads up to 63 rows past
  // its end (masked columns). m0 follows it -> in-workspace, safe. GLU also
  // reads 1 row before/after its x buffer (taps) -> in-workspace, masked.
  f16* wtg    = (f16*)alloc(8ull * 512 * 768 * 2);
  f16* wt0    = (f16*)alloc(256ull * 288 * 2);
  float* phsq = (float*)alloc(16416ull * 4);
  f16* p0     = (f16*)alloc(32ull * 513 * 256 * 2);
  f16* m0     = (f16*)alloc(32ull * 2000 * 256 * 2);
  f16* m1     = (f16*)alloc(32ull * 2000 * 256 * 2);
  f16* p1  = m1;        // ph ping buffer (mel ping is dead by then)
  f16* phT = m1;        // 9.4 MB <= 32.8 MB, used after ph GLUs done

  prep_wtglu_kernel<<<4096, 256, 0, stream>>>(mel_w, ph_w, wtg);
  prep_wt0_kernel<<<288, 256, 0, stream>>>(mel_conv_w, wt0);
  embed_kernel<<<dim3(513, 32), 64, 0, stream>>>(phonemes, embedding, p0);
  conv0_kernel<<<dim3(32, 4, 32), 256, 0, stream>>>(mels, wt0, mel_conv_b, m0);

  const size_t WL = 512ull * 768;
  // mel encoder: 4 GLU blocks (mask: t >= mel_lens[b])
  glu_kernel<<<dim3(16, 4, 32), 256, 0, stream>>>(m0, wtg + 0 * WL, mel_b + 0 * 512, m1, mel_lens, 0, 2000);
  glu_kernel<<<dim3(16, 4, 32), 256, 0, stream>>>(m1, wtg + 1 * WL, mel_b + 1 * 512, m0, mel_lens, 0, 2000);
  glu_kernel<<<dim3(16, 4, 32), 256, 0, stream>>>(m0, wtg + 2 * WL, mel_b + 2 * 512, m1, mel_lens, 0, 2000);
  glu_kernel<<<dim3(16, 4, 32), 256, 0, stream>>>(m1, wtg + 3 * WL, mel_b + 3 * 512, m0, mel_lens, 0, 2000);
  // phoneme encoder: 4 GLU blocks (mask: s > phoneme_lens[b])
  glu_kernel<<<dim3(5, 4, 32), 256, 0, stream>>>(p0, wtg + 4 * WL, ph_b + 0 * 512, p1, ph_lens, 1, 513);
  glu_kernel<<<dim3(5, 4, 32), 256, 0, stream>>>(p1, wtg + 5 * WL, ph_b + 1 * 512, p0, ph_lens, 1, 513);
  glu_kernel<<<dim3(5, 4, 32), 256, 0, stream>>>(p0, wtg + 6 * WL, ph_b + 2 * 512, p1, ph_lens, 1, 513);
  glu_kernel<<<dim3(5, 4, 32), 256, 0, stream>>>(p1, wtg + 7 * WL, ph_b + 3 * 512, p0, ph_lens, 1, 513);

  transpose_kernel<<<dim3(9, 4, 32), 256, 0, stream>>>(p0, phT);
  sqnorm_kernel<<<4104, 256, 0, stream>>>(p0, phsq, 16416);
  flash_kernel<<<dim3(1024), 256, 0, stream>>>(m0, p0, phT, phsq, ph_lens, out);
}

// Round 8
// 715.940 us; speedup vs baseline: 1.5385x; 1.0820x over previous
//
#include <hip/hip_runtime.h>

typedef _Float16 f16;
typedef __attribute__((ext_vector_type(8))) _Float16 half8;
typedef __attribute__((ext_vector_type(4))) _Float16 half4;
typedef __attribute__((ext_vector_type(4))) float f32x4;

__device__ inline f32x4 mfma16(half8 a, half8 b, f32x4 c) {
  return __builtin_amdgcn_mfma_f32_16x16x32_f16(a, b, c, 0, 0, 0);
}

// ---------------- weight prep ----------------
// GLU weights: Wt[l][r][tap*256+i] (f16), rows reordered so each 32-row group
// is 16 a-channels then 16 g-channels. One block per (l,r) row.
__global__ void prep_wtglu_kernel(const float* __restrict__ mel_w,
                                  const float* __restrict__ ph_w,
                                  f16* __restrict__ wt) {
  int bid = blockIdx.x;          // l*512 + r
  int l = bid >> 9, r = bid & 511;
  int tid = threadIdx.x;         // 0..255 = input channel i
  int n32 = r >> 5, j = r & 31;
  int ch = (j < 16) ? (n32 * 16 + j) : (256 + n32 * 16 + (j - 16));
  const float* src = ((l < 4) ? (mel_w + (size_t)l * 512 * 256 * 3)
                              : (ph_w + (size_t)(l - 4) * 512 * 256 * 3)) +
                     (size_t)ch * 768;
  f16* dst = wt + (size_t)bid * 768;
  float a0 = src[tid * 3], a1 = src[tid * 3 + 1], a2 = src[tid * 3 + 2];
  dst[tid] = (f16)a0;
  dst[256 + tid] = (f16)a1;
  dst[512 + tid] = (f16)a2;
}

// mel conv0 weights: Wt0[o][tap*96+i] (f16), channels padded 80->96 with zeros.
__global__ void prep_wt0_kernel(const float* __restrict__ w, f16* __restrict__ wt0) {
  int idx = blockIdx.x * 256 + threadIdx.x;
  const int total = 256 * 288;
  if (idx >= total) return;
  int o = idx / 288, k = idx % 288;
  int tap = k / 96, i = k % 96;
  wt0[idx] = (i < 80) ? (f16)w[((size_t)o * 80 + i) * 3 + tap] : (f16)0.f;
}

// ---------------- embedding (with blank prepend), f32 -> f16 ----------------
__global__ void embed_kernel(const int* __restrict__ phon, const float* __restrict__ emb,
                             f16* __restrict__ out) {
  int s = blockIdx.x, b = blockIdx.y;
  int lane = threadIdx.x;
  int tok = (s == 0) ? 0 : phon[b * 512 + (s - 1)];
  float4 f = *(const float4*)(emb + (size_t)tok * 256 + lane * 4);
  half4 h = {(f16)f.x, (f16)f.y, (f16)f.z, (f16)f.w};
  *(half4*)(out + ((size_t)b * 513 + s) * 256 + lane * 4) = h;
}

// ---------------- mel conv0 (K = 3 taps x 96 padded ch) ----------------
__global__ __launch_bounds__(256) void conv0_kernel(
    const float* __restrict__ mels, const f16* __restrict__ wt0,
    const float* __restrict__ bias, f16* __restrict__ out) {
  __shared__ f16 xs[66 * 104];
  __shared__ f16 ws[64 * 104];
  const int tid = threadIdx.x;
  const int b = blockIdx.z;
  const int t0 = blockIdx.x * 64;
  const int by = blockIdx.y;  // 0..3 (64 out-ch each)

  for (int idx = tid; idx < 66 * 24; idx += 256) {
    int r = idx / 24, v = idx % 24;
    int t = t0 - 1 + r;
    half4 h = {0.f, 0.f, 0.f, 0.f};
    if (t >= 0 && t < 2000 && v < 20) {
      float4 f = *(const float4*)(mels + ((size_t)b * 2000 + t) * 80 + v * 4);
      h[0] = (f16)f.x; h[1] = (f16)f.y; h[2] = (f16)f.z; h[3] = (f16)f.w;
    }
    *(half4*)(xs + r * 104 + v * 4) = h;
  }
  const int lane = tid & 63, wv = tid >> 6;
  const int wr = wv >> 1, wc = wv & 1;
  const int l15 = lane & 15, q = lane >> 4;
  f32x4 acc[2][2] = {};
  const f16* wrow = wt0 + (size_t)(by * 64) * 288;
  for (int tap = 0; tap < 3; ++tap) {
    __syncthreads();
    for (int idx = tid; idx < 64 * 12; idx += 256) {
      int r = idx / 12, v = idx % 12;
      *(half8*)(ws + r * 104 + v * 8) =
          *(const half8*)(wrow + (size_t)r * 288 + tap * 96 + v * 8);
    }
    __syncthreads();
#pragma unroll
    for (int s2 = 0; s2 < 3; ++s2) {
      int ch = s2 * 32 + q * 8;
      half8 a0 = *(const half8*)(xs + (32 * wr + l15 + tap) * 104 + ch);
      half8 a1 = *(const half8*)(xs + (32 * wr + 16 + l15 + tap) * 104 + ch);
      half8 b0 = *(const half8*)(ws + (32 * wc + l15) * 104 + ch);
      half8 b1 = *(const half8*)(ws + (32 * wc + 16 + l15) * 104 + ch);
      acc[0][0] = mfma16(a0, b0, acc[0][0]);
      acc[0][1] = mfma16(a0, b1, acc[0][1]);
      acc[1][0] = mfma16(a1, b0, acc[1][0]);
      acc[1][1] = mfma16(a1, b1, acc[1][1]);
    }
  }
#pragma unroll
  for (int rf = 0; rf < 2; ++rf)
#pragma unroll
    for (int cf = 0; cf < 2; ++cf) {
      int c = by * 64 + 32 * wc + 16 * cf + l15;
      float bb = bias[c];
#pragma unroll
      for (int r = 0; r < 4; ++r) {
        int t = t0 + 32 * wr + 16 * rf + 4 * q + r;
        if (t < 2000)
          out[((size_t)b * 2000 + t) * 256 + c] = (f16)(acc[rf][cf][r] + bb);
      }
    }
}

// ---------------- GLU v8: 128t x 128n block, X staged once per cb ----------
// Phase order (cb outer, tap inner; 12 phases): xs[132][72] holds the 130-row
// x 64-ch X window ONCE per cb (taps read row-shifted: lr = orow + tap) ->
// X global reads and xs ds_writes cut 3x vs v4. W reg-prefetch dbuf as v4.
// t-tile rotated per batch (tt = (x+b) % TT) to decorrelate t0 from CU id so
// the masked-block early-out converts to wall time under quasi-static
// workgroup assignment. writeConst=0 (intermediate layers): fully-masked
// blocks return without writing (masked rows never read downstream);
// writeConst=1 (layers 4/8): they write the bias-derived constant.
// y = conv(x_masked) + b; out = (a * sigmoid(g) + x_masked) * sqrt(0.5)
__global__ __launch_bounds__(256) void glu_kernel(
    const f16* __restrict__ x, const f16* __restrict__ wt,
    const float* __restrict__ bias, f16* __restrict__ out,
    const int* __restrict__ lens, int lenAdd, int T, int TT, int writeConst) {
  __shared__ f16 xs[132 * 72];
  __shared__ f16 ws2[128 * 72];
  const int tid = threadIdx.x;
  const int b = blockIdx.z;
  const int tt = (blockIdx.x + b) % TT;   // per-batch rotation (bijective)
  const int t0 = tt * 128;
  const int by = blockIdx.y;  // 0..3 (128 reordered rows each)
  int thr = lens[b] + lenAdd;
  if (thr > T) thr = T;
  const size_t xbase = (size_t)b * T * 256;
  const int lane = tid & 63, wv = tid >> 6;
  const int wr = wv >> 1, wc = wv & 1;   // wave tile 64t x 64n
  const int l15 = lane & 15, q = lane >> 4;

  if (t0 > thr) {
    // all conv inputs masked-zero -> constant output (only final layers write)
    if (writeConst) {
#pragma unroll
      for (int p = 0; p < 2; ++p) {
        int n32 = by * 4 + wc * 2 + p;
        int c = n32 * 16 + l15;
        float ba = bias[c], bg = bias[256 + c];
        f16 o = (f16)((ba * (1.0f / (1.0f + __expf(-bg)))) * 0.70710678118f);
#pragma unroll
        for (int mt = 0; mt < 4; ++mt)
#pragma unroll
          for (int rr = 0; rr < 4; ++rr) {
            int t = t0 + wr * 64 + mt * 16 + q * 4 + rr;
            if (t < T) out[xbase + (size_t)t * 256 + c] = o;
          }
      }
    }
    return;
  }

  f32x4 acc[4][4] = {};
  const f16* wrow = wt + (size_t)(by * 128) * 768;
  const int r_st = tid >> 3, v_st = tid & 7;

  // X stage: 130 rows (t0-1 .. t0+128) x 64 ch = 1040 half8 slots
  half8 xr[5], wreg[4];
  auto loadX = [&](int cb) {
#pragma unroll
    for (int it = 0; it < 5; ++it) {
      int idx = tid + it * 256;
      half8 val = {};
      if (idx < 1040) {
        int lr = idx >> 3, v = idx & 7;
        int trow = t0 - 1 + lr;
        if (trow >= 0 && trow < thr)
          val = *(const half8*)(x + xbase + (size_t)trow * 256 + cb * 64 + v * 8);
      }
      xr[it] = val;
    }
  };
  auto storeX = [&]() {
#pragma unroll
    for (int it = 0; it < 5; ++it) {
      int idx = tid + it * 256;
      if (idx < 1040) {
        int lr = idx >> 3, v = idx & 7;
        *(half8*)(xs + lr * 72 + v * 8) = xr[it];
      }
    }
  };
  auto loadW = [&](int tap, int cb) {
#pragma unroll
    for (int it = 0; it < 4; ++it) {
      int r = r_st + 32 * it;
      wreg[it] = *(const half8*)(wrow + (size_t)r * 768 + tap * 256 + cb * 64 + v_st * 8);
    }
  };
  auto storeW = [&]() {
#pragma unroll
    for (int it = 0; it < 4; ++it)
      *(half8*)(ws2 + (r_st + 32 * it) * 72 + v_st * 8) = wreg[it];
  };

  loadX(0);
  loadW(0, 0);

  for (int p = 0; p < 12; ++p) {
    const int cb = p / 3, tap = p - cb * 3;
    __syncthreads();   // previous phase's LDS reads done
    if (tap == 0) storeX();
    storeW();
    __syncthreads();   // LDS ready
    if (p < 11) {      // prefetch next phase (in flight during MFMA)
      int np = p + 1, ncb = np / 3, ntap = np - ncb * 3;
      if (ntap == 0) loadX(ncb);
      loadW(ntap, ncb);
    }

    half8 af[4][2];
#pragma unroll
    for (int mt = 0; mt < 4; ++mt)
#pragma unroll
      for (int kc = 0; kc < 2; ++kc)
        af[mt][kc] = *(const half8*)(xs + (wr * 64 + mt * 16 + l15 + tap) * 72 + kc * 32 + q * 8);
#pragma unroll
    for (int nt = 0; nt < 4; ++nt) {
      half8 b0 = *(const half8*)(ws2 + (wc * 64 + nt * 16 + l15) * 72 + q * 8);
      half8 b1 = *(const half8*)(ws2 + (wc * 64 + nt * 16 + l15) * 72 + 32 + q * 8);
#pragma unroll
      for (int mt = 0; mt < 4; ++mt) {
        acc[mt][nt] = mfma16(af[mt][0], b0, acc[mt][nt]);
        acc[mt][nt] = mfma16(af[mt][1], b1, acc[mt][nt]);
      }
    }
  }

  // epilogue: nt pairs (0,1),(2,3) are (a,g) channel groups (rows reordered)
#pragma unroll
  for (int p = 0; p < 2; ++p) {
    int n32 = by * 4 + wc * 2 + p;
    int c = n32 * 16 + l15;
    float ba = bias[c], bg = bias[256 + c];
#pragma unroll
    for (int mt = 0; mt < 4; ++mt) {
#pragma unroll
      for (int rr = 0; rr < 4; ++rr) {
        int t = t0 + wr * 64 + mt * 16 + q * 4 + rr;
        if (t < T && (writeConst || t < thr)) {
          float a = acc[mt][2 * p][rr] + ba;
          float g = acc[mt][2 * p + 1][rr] + bg;
          float xm = (t < thr) ? (float)x[xbase + (size_t)t * 256 + c] : 0.f;
          float o = (a * (1.0f / (1.0f + __expf(-g))) + xm) * 0.70710678118f;
          out[xbase + (size_t)t * 256 + c] = (f16)o;
        }
      }
    }
  }
}

// ---------------- transpose ph_enc -> phT [b][256 d][576 s] (zeros padded) ----------------
__global__ __launch_bounds__(256) void transpose_kernel(const f16* __restrict__ ph,
                                                        f16* __restrict__ phT) {
  __shared__ f16 tile[64 * 72];
  const int tid = threadIdx.x;
  const int b = blockIdx.z, s0 = blockIdx.x * 64, d0 = blockIdx.y * 64;
#pragma unroll
  for (int it = 0; it < 2; ++it) {
    int idx = tid + it * 256;
    int r = idx >> 3, v = idx & 7;
    int s = s0 + r;
    half8 val = {};
    if (s < 513) val = *(const half8*)(ph + ((size_t)b * 513 + s) * 256 + d0 + v * 8);
    *(half8*)(tile + r * 72 + v * 8) = val;
  }
  __syncthreads();
#pragma unroll
  for (int it = 0; it < 2; ++it) {
    int idx = tid + it * 256;
    int r = idx >> 3, v = idx & 7;   // r = local d, v*8+j = local s
    half8 val;
#pragma unroll
    for (int j2 = 0; j2 < 8; ++j2) val[j2] = tile[(v * 8 + j2) * 72 + r];
    *(half8*)(phT + ((size_t)b * 256 + d0 + r) * 576 + s0 + v * 8) = val;
  }
}

// ---------------- squared norms (phoneme side; mel_sq cancels in softmax) ----------------
__global__ void sqnorm_kernel(const f16* __restrict__ x, float* __restrict__ sq, int nrows) {
  int row = blockIdx.x * 4 + (threadIdx.x >> 6);
  int lane = threadIdx.x & 63;
  if (row >= nrows) return;
  const f16* p = x + (size_t)row * 256;
  float v = 0.f;
  for (int i = lane; i < 256; i += 64) { float f = (float)p[i]; v += f * f; }
  for (int off = 32; off > 0; off >>= 1) v += __shfl_down(v, off);
  if (lane == 0) sq[row] = v;
}

// ---------------- fused dist+softmax+context + mel copy (flash-style) ----------------
// v7: r0's proven structure (V^T reg-prefetch -> LDS vt, 2 barriers/kt,
// K direct from global with 4 parallel sc chains) + XCD-bijective swizzle
// (4 batches/XCD -> ph+phT working set ~3.4MB L2-resident per XCD) +
// one-time phs preload + s_setprio(1) around MFMA clusters.
// scores(t,s) = 2*dot(mel_t, ph_s) - |ph_s|^2  (row-constant -|mel_t|^2 dropped).
// K reads for s in [513,576) hit in-workspace garbage but are masked pre-max.
__global__ __launch_bounds__(256) void flash_kernel(
    const f16* __restrict__ mel, const f16* __restrict__ ph,
    const f16* __restrict__ phT, const float* __restrict__ phsq,
    const int* __restrict__ plens, float* __restrict__ out) {
  __shared__ f16 vt[256 * 72];   // V^T tile [d][s-local]
  __shared__ f16 ps[4][16 * 72]; // per-wave P 16x64 (wave-private)
  __shared__ float phs[576];
  const int tid = threadIdx.x;
  // XCD swizzle (bijective): b = (lin>>8)*8 + (lin&7), tt = (lin>>3)&31.
  const int lin = blockIdx.x;
  const int b = ((lin >> 8) << 3) | (lin & 7);
  const int t0 = ((lin >> 3) & 31) * 64;
  const int lane = tid & 63, wv = tid >> 6;
  const int l15 = lane & 15, q = lane >> 4;
  const int plen = plens[b];

  for (int idx = tid; idx < 576; idx += 256)
    phs[idx] = (idx < 513) ? phsq[b * 513 + idx] : 0.f;

  // Q fragments in registers (wave's 16 rows)
  const int tq = t0 + 16 * wv + l15;
  half8 qf[8];
  {
    const f16* qrow = mel + ((size_t)b * 2000 + ((tq < 2000) ? tq : 0)) * 256;
#pragma unroll
    for (int c = 0; c < 8; ++c) qf[c] = *(const half8*)(qrow + c * 32 + q * 8);
    if (tq >= 2000) {
      half8 z = {};
#pragma unroll
      for (int c = 0; c < 8; ++c) qf[c] = z;
    }
  }
  // fused copymel: out[..., 0:256] = mel_enc (from qf, f16 -> f32)
  if (tq < 2000) {
    float* orow = out + ((size_t)b * 2000 + tq) * 512;
#pragma unroll
    for (int c = 0; c < 8; ++c) {
      half8 h = qf[c];
      float4 f0 = {(float)h[0], (float)h[1], (float)h[2], (float)h[3]};
      float4 f1 = {(float)h[4], (float)h[5], (float)h[6], (float)h[7]};
      *(float4*)(orow + c * 32 + q * 8) = f0;
      *(float4*)(orow + c * 32 + q * 8 + 4) = f1;
    }
  }

  half8 vreg[8];
  const int d_st = tid >> 3, v_st = tid & 7;
  auto loadV = [&](int kt) {
#pragma unroll
    for (int it = 0; it < 8; ++it) {
      int d = d_st + 32 * it;
      vreg[it] = *(const half8*)(phT + ((size_t)b * 256 + d) * 576 + kt * 64 + v_st * 8);
    }
  };
  loadV(0);

  float mr[4], lr[4];
#pragma unroll
  for (int r = 0; r < 4; ++r) { mr[r] = -3.0e38f; lr[r] = 0.f; }
  f32x4 acc[16] = {};
  f16* pw = ps[wv];

#pragma unroll 1
  for (int kt = 0; kt < 9; ++kt) {
    const int s0 = kt * 64;
    __syncthreads();  // prev iter's PV reads of vt done (kt=0: phs ready too)
#pragma unroll
    for (int it = 0; it < 8; ++it)
      *(half8*)(vt + (d_st + 32 * it) * 72 + v_st * 8) = vreg[it];
    __syncthreads();  // vt ready
    if (kt < 8) loadV(kt + 1);  // in flight during compute

    // QK^T: B-frags direct from global (identical across waves -> L1 hits)
    const f16* krow[4];
#pragma unroll
    for (int cf = 0; cf < 4; ++cf)
      krow[cf] = ph + ((size_t)b * 513 + (s0 + cf * 16 + l15)) * 256 + q * 8;
    f32x4 sc[4] = {};
    __builtin_amdgcn_s_setprio(1);
#pragma unroll
    for (int c = 0; c < 8; ++c) {
#pragma unroll
      for (int cf = 0; cf < 4; ++cf) {
        half8 bf = *(const half8*)(krow[cf] + c * 32);
        sc[cf] = mfma16(qf[c], bf, sc[cf]);
      }
    }
    __builtin_amdgcn_s_setprio(0);
    // score epilogue + online softmax (reduce across 16-lane quads)
    float p[4][4];
    float rmax[4] = {-3.0e38f, -3.0e38f, -3.0e38f, -3.0e38f};
#pragma unroll
    for (int cf = 0; cf < 4; ++cf) {
      int sloc = cf * 16 + l15;
      int s = s0 + sloc;
      bool msk = (s > plen) || (s >= 513);
      float p2 = phs[s0 + sloc];
#pragma unroll
      for (int r = 0; r < 4; ++r) {
        float v = 2.0f * sc[cf][r] - p2;
        if (msk) v = -1.0e9f;
        p[cf][r] = v;
        rmax[r] = fmaxf(rmax[r], v);
      }
    }
#pragma unroll
    for (int r = 0; r < 4; ++r)
#pragma unroll
      for (int off = 1; off < 16; off <<= 1)
        rmax[r] = fmaxf(rmax[r], __shfl_xor(rmax[r], off));
    float alpha[4];
#pragma unroll
    for (int r = 0; r < 4; ++r) {
      float mn = fmaxf(mr[r], rmax[r]);
      alpha[r] = __expf(mr[r] - mn);
      mr[r] = mn;
      float rs = 0.f;
#pragma unroll
      for (int cf = 0; cf < 4; ++cf) {
        float e = __expf(p[cf][r] - mn);
        p[cf][r] = e;
        rs += e;
      }
#pragma unroll
      for (int off = 1; off < 16; off <<= 1) rs += __shfl_xor(rs, off);
      lr[r] = lr[r] * alpha[r] + rs;
    }
#pragma unroll
    for (int dt = 0; dt < 16; ++dt)
#pragma unroll
      for (int r = 0; r < 4; ++r) acc[dt][r] *= alpha[r];
    // P to wave-private LDS (C-layout), read back in A-layout (no barrier:
    // wave-private region, lgkmcnt orders the ds ops within the wave)
#pragma unroll
    for (int cf = 0; cf < 4; ++cf)
#pragma unroll
      for (int r = 0; r < 4; ++r)
        pw[(q * 4 + r) * 72 + cf * 16 + l15] = (f16)p[cf][r];
    // PV: 16 t-rows x 256 d-cols, K = 64 (2 chunks), V from LDS
#pragma unroll
    for (int kc = 0; kc < 2; ++kc) {
      half8 pa = *(const half8*)(pw + l15 * 72 + kc * 32 + q * 8);
      __builtin_amdgcn_s_setprio(1);
#pragma unroll
      for (int dt = 0; dt < 16; ++dt) {
        half8 vb = *(const half8*)(vt + (dt * 16 + l15) * 72 + kc * 32 + q * 8);
        acc[dt] = mfma16(pa, vb, acc[dt]);
      }
      __builtin_amdgcn_s_setprio(0);
    }
  }
  float inv[4];
#pragma unroll
  for (int r = 0; r < 4; ++r) inv[r] = 1.0f / lr[r];
#pragma unroll
  for (int dt = 0; dt < 16; ++dt)
#pragma unroll
    for (int r = 0; r < 4; ++r) {
      int t = t0 + 16 * wv + q * 4 + r;
      if (t < 2000) {
        int d = dt * 16 + l15;
        out[((size_t)b * 2000 + t) * 512 + 256 + d] = acc[dt][r] * inv[r];
      }
    }
}

extern "C" void kernel_launch(void* const* d_in, const int* in_sizes, int n_in,
                              void* d_out, int out_size, void* d_ws, size_t ws_size,
                              hipStream_t stream) {
  (void)in_sizes; (void)n_in; (void)out_size; (void)ws_size;
  const float* mels       = (const float*)d_in[0];
  const int*   phonemes   = (const int*)d_in[1];
  const int*   mel_lens   = (const int*)d_in[2];
  const int*   ph_lens    = (const int*)d_in[3];
  const float* embedding  = (const float*)d_in[4];
  const float* mel_conv_w = (const float*)d_in[5];
  const float* mel_conv_b = (const float*)d_in[6];
  const float* ph_w       = (const float*)d_in[7];
  const float* ph_b       = (const float*)d_in[8];
  const float* mel_w      = (const float*)d_in[9];
  const float* mel_b      = (const float*)d_in[10];
  float* out = (float*)d_out;

  char* wsp = (char*)d_ws;
  size_t off = 0;
  auto alloc = [&](size_t bytes) -> void* {
    void* p = wsp + off;
    off = (off + bytes + 255) & ~(size_t)255;
    return p;
  };
  // NOTE: p0 must NOT be the last allocation — flash reads up to 63 rows past
  // its end (masked columns). m0 follows it -> in-workspace, safe. GLU also
  // reads 1 row before/after its x buffer (taps) -> in-workspace, masked.
  f16* wtg    = (f16*)alloc(8ull * 512 * 768 * 2);
  f16* wt0    = (f16*)alloc(256ull * 288 * 2);
  float* phsq = (float*)alloc(16416ull * 4);
  f16* p0     = (f16*)alloc(32ull * 513 * 256 * 2);
  f16* m0     = (f16*)alloc(32ull * 2000 * 256 * 2);
  f16* m1     = (f16*)alloc(32ull * 2000 * 256 * 2);
  f16* p1  = m1;        // ph ping buffer (mel ping is dead by then)
  f16* phT = m1;        // 9.4 MB <= 32.8 MB, used after ph GLUs done

  prep_wtglu_kernel<<<4096, 256, 0, stream>>>(mel_w, ph_w, wtg);
  prep_wt0_kernel<<<288, 256, 0, stream>>>(mel_conv_w, wt0);
  embed_kernel<<<dim3(513, 32), 64, 0, stream>>>(phonemes, embedding, p0);
  conv0_kernel<<<dim3(32, 4, 32), 256, 0, stream>>>(mels, wt0, mel_conv_b, m0);

  const size_t WL = 512ull * 768;
  // mel encoder: 4 GLU blocks (mask: t >= mel_lens[b]); only layer 4 writes
  // the masked-region constant (intermediate masked rows are never read).
  glu_kernel<<<dim3(16, 4, 32), 256, 0, stream>>>(m0, wtg + 0 * WL, mel_b + 0 * 512, m1, mel_lens, 0, 2000, 16, 0);
  glu_kernel<<<dim3(16, 4, 32), 256, 0, stream>>>(m1, wtg + 1 * WL, mel_b + 1 * 512, m0, mel_lens, 0, 2000, 16, 0);
  glu_kernel<<<dim3(16, 4, 32), 256, 0, stream>>>(m0, wtg + 2 * WL, mel_b + 2 * 512, m1, mel_lens, 0, 2000, 16, 0);
  glu_kernel<<<dim3(16, 4, 32), 256, 0, stream>>>(m1, wtg + 3 * WL, mel_b + 3 * 512, m0, mel_lens, 0, 2000, 16, 1);
  // phoneme encoder: 4 GLU blocks (mask: s > phoneme_lens[b])
  glu_kernel<<<dim3(5, 4, 32), 256, 0, stream>>>(p0, wtg + 4 * WL, ph_b + 0 * 512, p1, ph_lens, 1, 513, 5, 0);
  glu_kernel<<<dim3(5, 4, 32), 256, 0, stream>>>(p1, wtg + 5 * WL, ph_b + 1 * 512, p0, ph_lens, 1, 513, 5, 0);
  glu_kernel<<<dim3(5, 4, 32), 256, 0, stream>>>(p0, wtg + 6 * WL, ph_b + 2 * 512, p1, ph_lens, 1, 513, 5, 0);
  glu_kernel<<<dim3(5, 4, 32), 256, 0, stream>>>(p1, wtg + 7 * WL, ph_b + 3 * 512, p0, ph_lens, 1, 513, 5, 1);

  transpose_kernel<<<dim3(9, 4, 32), 256, 0, stream>>>(p0, phT);
  sqnorm_kernel<<<4104, 256, 0, stream>>>(p0, phsq, 16416);
  flash_kernel<<<dim3(32 * 32), 256, 0, stream>>>(m0, p0, phT, phsq, ph_lens, out);
}

// Round 9
// 681.501 us; speedup vs baseline: 1.6163x; 1.0505x over previous
//
#include <hip/hip_runtime.h>

typedef _Float16 f16;
typedef __attribute__((ext_vector_type(8))) _Float16 half8;
typedef __attribute__((ext_vector_type(4))) _Float16 half4;
typedef __attribute__((ext_vector_type(4))) float f32x4;

__device__ inline f32x4 mfma16(half8 a, half8 b, f32x4 c) {
  return __builtin_amdgcn_mfma_f32_16x16x32_f16(a, b, c, 0, 0, 0);
}

// ---------------- weight prep ----------------
// GLU weights: Wt[l][r][tap*256+i] (f16), rows reordered so each 32-row group
// is 16 a-channels then 16 g-channels. One block per (l,r) row.
__global__ void prep_wtglu_kernel(const float* __restrict__ mel_w,
                                  const float* __restrict__ ph_w,
                                  f16* __restrict__ wt) {
  int bid = blockIdx.x;          // l*512 + r
  int l = bid >> 9, r = bid & 511;
  int tid = threadIdx.x;         // 0..255 = input channel i
  int n32 = r >> 5, j = r & 31;
  int ch = (j < 16) ? (n32 * 16 + j) : (256 + n32 * 16 + (j - 16));
  const float* src = ((l < 4) ? (mel_w + (size_t)l * 512 * 256 * 3)
                              : (ph_w + (size_t)(l - 4) * 512 * 256 * 3)) +
                     (size_t)ch * 768;
  f16* dst = wt + (size_t)bid * 768;
  float a0 = src[tid * 3], a1 = src[tid * 3 + 1], a2 = src[tid * 3 + 2];
  dst[tid] = (f16)a0;
  dst[256 + tid] = (f16)a1;
  dst[512 + tid] = (f16)a2;
}

// mel conv0 weights: Wt0[o][tap*96+i] (f16), channels padded 80->96 with zeros.
__global__ void prep_wt0_kernel(const float* __restrict__ w, f16* __restrict__ wt0) {
  int idx = blockIdx.x * 256 + threadIdx.x;
  const int total = 256 * 288;
  if (idx >= total) return;
  int o = idx / 288, k = idx % 288;
  int tap = k / 96, i = k % 96;
  wt0[idx] = (i < 80) ? (f16)w[((size_t)o * 80 + i) * 3 + tap] : (f16)0.f;
}

// ---------------- embedding (with blank prepend), f32 -> f16 ----------------
__global__ void embed_kernel(const int* __restrict__ phon, const float* __restrict__ emb,
                             f16* __restrict__ out) {
  int s = blockIdx.x, b = blockIdx.y;
  int lane = threadIdx.x;
  int tok = (s == 0) ? 0 : phon[b * 512 + (s - 1)];
  float4 f = *(const float4*)(emb + (size_t)tok * 256 + lane * 4);
  half4 h = {(f16)f.x, (f16)f.y, (f16)f.z, (f16)f.w};
  *(half4*)(out + ((size_t)b * 513 + s) * 256 + lane * 4) = h;
}

// ---------------- mel conv0 (K = 3 taps x 96 padded ch) ----------------
__global__ __launch_bounds__(256) void conv0_kernel(
    const float* __restrict__ mels, const f16* __restrict__ wt0,
    const float* __restrict__ bias, f16* __restrict__ out) {
  __shared__ f16 xs[66 * 104];
  __shared__ f16 ws[64 * 104];
  const int tid = threadIdx.x;
  const int b = blockIdx.z;
  const int t0 = blockIdx.x * 64;
  const int by = blockIdx.y;  // 0..3 (64 out-ch each)

  for (int idx = tid; idx < 66 * 24; idx += 256) {
    int r = idx / 24, v = idx % 24;
    int t = t0 - 1 + r;
    half4 h = {0.f, 0.f, 0.f, 0.f};
    if (t >= 0 && t < 2000 && v < 20) {
      float4 f = *(const float4*)(mels + ((size_t)b * 2000 + t) * 80 + v * 4);
      h[0] = (f16)f.x; h[1] = (f16)f.y; h[2] = (f16)f.z; h[3] = (f16)f.w;
    }
    *(half4*)(xs + r * 104 + v * 4) = h;
  }
  const int lane = tid & 63, wv = tid >> 6;
  const int wr = wv >> 1, wc = wv & 1;
  const int l15 = lane & 15, q = lane >> 4;
  f32x4 acc[2][2] = {};
  const f16* wrow = wt0 + (size_t)(by * 64) * 288;
  for (int tap = 0; tap < 3; ++tap) {
    __syncthreads();
    for (int idx = tid; idx < 64 * 12; idx += 256) {
      int r = idx / 12, v = idx % 12;
      *(half8*)(ws + r * 104 + v * 8) =
          *(const half8*)(wrow + (size_t)r * 288 + tap * 96 + v * 8);
    }
    __syncthreads();
#pragma unroll
    for (int s2 = 0; s2 < 3; ++s2) {
      int ch = s2 * 32 + q * 8;
      half8 a0 = *(const half8*)(xs + (32 * wr + l15 + tap) * 104 + ch);
      half8 a1 = *(const half8*)(xs + (32 * wr + 16 + l15 + tap) * 104 + ch);
      half8 b0 = *(const half8*)(ws + (32 * wc + l15) * 104 + ch);
      half8 b1 = *(const half8*)(ws + (32 * wc + 16 + l15) * 104 + ch);
      acc[0][0] = mfma16(a0, b0, acc[0][0]);
      acc[0][1] = mfma16(a0, b1, acc[0][1]);
      acc[1][0] = mfma16(a1, b0, acc[1][0]);
      acc[1][1] = mfma16(a1, b1, acc[1][1]);
    }
  }
#pragma unroll
  for (int rf = 0; rf < 2; ++rf)
#pragma unroll
    for (int cf = 0; cf < 2; ++cf) {
      int c = by * 64 + 32 * wc + 16 * cf + l15;
      float bb = bias[c];
#pragma unroll
      for (int r = 0; r < 4; ++r) {
        int t = t0 + 32 * wr + 16 * rf + 4 * q + r;
        if (t < 2000)
          out[((size_t)b * 2000 + t) * 256 + c] = (f16)(acc[rf][cf][r] + bb);
      }
    }
}

// ---------------- GLU v9 body: v8 structure, callable for mel or ph part ----
// 128t x 128n block, X staged once per cb (12 phases, taps read row-shifted),
// W reg-prefetch dbuf, per-batch t-tile rotation, masked-block early-out.
__device__ __forceinline__ void glu_body(
    f16* xs, f16* ws2,
    const f16* __restrict__ x, const f16* __restrict__ wt,
    const float* __restrict__ bias, f16* __restrict__ out,
    const int* __restrict__ lens, int lenAdd, int T, int TT, int writeConst,
    int bx, int by, int b) {
  const int tid = threadIdx.x;
  const int tt = (bx + b) % TT;   // per-batch rotation (bijective)
  const int t0 = tt * 128;
  int thr = lens[b] + lenAdd;
  if (thr > T) thr = T;
  const size_t xbase = (size_t)b * T * 256;
  const int lane = tid & 63, wv = tid >> 6;
  const int wr = wv >> 1, wc = wv & 1;   // wave tile 64t x 64n
  const int l15 = lane & 15, q = lane >> 4;

  if (t0 > thr) {
    // all conv inputs masked-zero -> constant output (only final layers write)
    if (writeConst) {
#pragma unroll
      for (int p = 0; p < 2; ++p) {
        int n32 = by * 4 + wc * 2 + p;
        int c = n32 * 16 + l15;
        float ba = bias[c], bg = bias[256 + c];
        f16 o = (f16)((ba * (1.0f / (1.0f + __expf(-bg)))) * 0.70710678118f);
#pragma unroll
        for (int mt = 0; mt < 4; ++mt)
#pragma unroll
          for (int rr = 0; rr < 4; ++rr) {
            int t = t0 + wr * 64 + mt * 16 + q * 4 + rr;
            if (t < T) out[xbase + (size_t)t * 256 + c] = o;
          }
      }
    }
    return;
  }

  f32x4 acc[4][4] = {};
  const f16* wrow = wt + (size_t)(by * 128) * 768;
  const int r_st = tid >> 3, v_st = tid & 7;

  // X stage: 130 rows (t0-1 .. t0+128) x 64 ch = 1040 half8 slots
  half8 xr[5], wreg[4];
  auto loadX = [&](int cb) {
#pragma unroll
    for (int it = 0; it < 5; ++it) {
      int idx = tid + it * 256;
      half8 val = {};
      if (idx < 1040) {
        int lr = idx >> 3, v = idx & 7;
        int trow = t0 - 1 + lr;
        if (trow >= 0 && trow < thr)
          val = *(const half8*)(x + xbase + (size_t)trow * 256 + cb * 64 + v * 8);
      }
      xr[it] = val;
    }
  };
  auto storeX = [&]() {
#pragma unroll
    for (int it = 0; it < 5; ++it) {
      int idx = tid + it * 256;
      if (idx < 1040) {
        int lr = idx >> 3, v = idx & 7;
        *(half8*)(xs + lr * 72 + v * 8) = xr[it];
      }
    }
  };
  auto loadW = [&](int tap, int cb) {
#pragma unroll
    for (int it = 0; it < 4; ++it) {
      int r = r_st + 32 * it;
      wreg[it] = *(const half8*)(wrow + (size_t)r * 768 + tap * 256 + cb * 64 + v_st * 8);
    }
  };
  auto storeW = [&]() {
#pragma unroll
    for (int it = 0; it < 4; ++it)
      *(half8*)(ws2 + (r_st + 32 * it) * 72 + v_st * 8) = wreg[it];
  };

  loadX(0);
  loadW(0, 0);

  for (int p = 0; p < 12; ++p) {
    const int cb = p / 3, tap = p - cb * 3;
    __syncthreads();   // previous phase's LDS reads done
    if (tap == 0) storeX();
    storeW();
    __syncthreads();   // LDS ready
    if (p < 11) {      // prefetch next phase (in flight during MFMA)
      int np = p + 1, ncb = np / 3, ntap = np - ncb * 3;
      if (ntap == 0) loadX(ncb);
      loadW(ntap, ncb);
    }

    half8 af[4][2];
#pragma unroll
    for (int mt = 0; mt < 4; ++mt)
#pragma unroll
      for (int kc = 0; kc < 2; ++kc)
        af[mt][kc] = *(const half8*)(xs + (wr * 64 + mt * 16 + l15 + tap) * 72 + kc * 32 + q * 8);
#pragma unroll
    for (int nt = 0; nt < 4; ++nt) {
      half8 b0 = *(const half8*)(ws2 + (wc * 64 + nt * 16 + l15) * 72 + q * 8);
      half8 b1 = *(const half8*)(ws2 + (wc * 64 + nt * 16 + l15) * 72 + 32 + q * 8);
#pragma unroll
      for (int mt = 0; mt < 4; ++mt) {
        acc[mt][nt] = mfma16(af[mt][0], b0, acc[mt][nt]);
        acc[mt][nt] = mfma16(af[mt][1], b1, acc[mt][nt]);
      }
    }
  }

  // epilogue: nt pairs (0,1),(2,3) are (a,g) channel groups (rows reordered)
#pragma unroll
  for (int p = 0; p < 2; ++p) {
    int n32 = by * 4 + wc * 2 + p;
    int c = n32 * 16 + l15;
    float ba = bias[c], bg = bias[256 + c];
#pragma unroll
    for (int mt = 0; mt < 4; ++mt) {
#pragma unroll
      for (int rr = 0; rr < 4; ++rr) {
        int t = t0 + wr * 64 + mt * 16 + q * 4 + rr;
        if (t < T && (writeConst || t < thr)) {
          float a = acc[mt][2 * p][rr] + ba;
          float g = acc[mt][2 * p + 1][rr] + bg;
          float xm = (t < thr) ? (float)x[xbase + (size_t)t * 256 + c] : 0.f;
          float o = (a * (1.0f / (1.0f + __expf(-g))) + xm) * 0.70710678118f;
          out[xbase + (size_t)t * 256 + c] = (f16)o;
        }
      }
    }
  }
}

// ---------------- fused GLU layer: mel part (2048 blocks) + ph part (640) ----
// The mel and phoneme encoder chains are independent until the flash kernel;
// fusing layer i of both into one dispatch lets the small ph blocks (launched
// last) backfill the mel dispatch's drain tail instead of serializing.
__global__ __launch_bounds__(256) void glu_fused_kernel(
    const f16* __restrict__ xm, const f16* __restrict__ wtm,
    const float* __restrict__ bm, f16* __restrict__ om,
    const int* __restrict__ mlens,
    const f16* __restrict__ xp, const f16* __restrict__ wtp,
    const float* __restrict__ bp, f16* __restrict__ op,
    const int* __restrict__ plens, int writeConst) {
  __shared__ f16 xs[132 * 72];
  __shared__ f16 ws2[128 * 72];
  const int lin = blockIdx.x;
  if (lin < 2048) {           // mel: 32b x 4y x 16x
    int b = lin >> 6, y = (lin >> 4) & 3, x = lin & 15;
    glu_body(xs, ws2, xm, wtm, bm, om, mlens, 0, 2000, 16, writeConst, x, y, b);
  } else {                    // ph: 32b x 4y x 5x
    int l2 = lin - 2048;
    int b = l2 / 20, r = l2 % 20, y = r / 5, x = r % 5;
    glu_body(xs, ws2, xp, wtp, bp, op, plens, 1, 513, 5, writeConst, x, y, b);
  }
}

// ---------------- transpose ph_enc -> phT [b][256 d][576 s] (zeros padded) ----------------
__global__ __launch_bounds__(256) void transpose_kernel(const f16* __restrict__ ph,
                                                        f16* __restrict__ phT) {
  __shared__ f16 tile[64 * 72];
  const int tid = threadIdx.x;
  const int b = blockIdx.z, s0 = blockIdx.x * 64, d0 = blockIdx.y * 64;
#pragma unroll
  for (int it = 0; it < 2; ++it) {
    int idx = tid + it * 256;
    int r = idx >> 3, v = idx & 7;
    int s = s0 + r;
    half8 val = {};
    if (s < 513) val = *(const half8*)(ph + ((size_t)b * 513 + s) * 256 + d0 + v * 8);
    *(half8*)(tile + r * 72 + v * 8) = val;
  }
  __syncthreads();
#pragma unroll
  for (int it = 0; it < 2; ++it) {
    int idx = tid + it * 256;
    int r = idx >> 3, v = idx & 7;   // r = local d, v*8+j = local s
    half8 val;
#pragma unroll
    for (int j2 = 0; j2 < 8; ++j2) val[j2] = tile[(v * 8 + j2) * 72 + r];
    *(half8*)(phT + ((size_t)b * 256 + d0 + r) * 576 + s0 + v * 8) = val;
  }
}

// ---------------- squared norms (phoneme side; mel_sq cancels in softmax) ----------------
__global__ void sqnorm_kernel(const f16* __restrict__ x, float* __restrict__ sq, int nrows) {
  int row = blockIdx.x * 4 + (threadIdx.x >> 6);
  int lane = threadIdx.x & 63;
  if (row >= nrows) return;
  const f16* p = x + (size_t)row * 256;
  float v = 0.f;
  for (int i = lane; i < 256; i += 64) { float f = (float)p[i]; v += f * f; }
  for (int off = 32; off > 0; off >>= 1) v += __shfl_down(v, off);
  if (lane == 0) sq[row] = v;
}

// ---------------- fused dist+softmax+context + mel copy (flash-style) ----------------
// v7: r0's proven structure (V^T reg-prefetch -> LDS vt, 2 barriers/kt,
// K direct from global with 4 parallel sc chains) + XCD-bijective swizzle
// (4 batches/XCD -> ph+phT working set ~3.4MB L2-resident per XCD) +
// one-time phs preload + s_setprio(1) around MFMA clusters.
// scores(t,s) = 2*dot(mel_t, ph_s) - |ph_s|^2  (row-constant -|mel_t|^2 dropped).
// K reads for s in [513,576) hit in-workspace garbage but are masked pre-max.
__global__ __launch_bounds__(256) void flash_kernel(
    const f16* __restrict__ mel, const f16* __restrict__ ph,
    const f16* __restrict__ phT, const float* __restrict__ phsq,
    const int* __restrict__ plens, float* __restrict__ out) {
  __shared__ f16 vt[256 * 72];   // V^T tile [d][s-local]
  __shared__ f16 ps[4][16 * 72]; // per-wave P 16x64 (wave-private)
  __shared__ float phs[576];
  const int tid = threadIdx.x;
  // XCD swizzle (bijective): b = (lin>>8)*8 + (lin&7), tt = (lin>>3)&31.
  const int lin = blockIdx.x;
  const int b = ((lin >> 8) << 3) | (lin & 7);
  const int t0 = ((lin >> 3) & 31) * 64;
  const int lane = tid & 63, wv = tid >> 6;
  const int l15 = lane & 15, q = lane >> 4;
  const int plen = plens[b];

  for (int idx = tid; idx < 576; idx += 256)
    phs[idx] = (idx < 513) ? phsq[b * 513 + idx] : 0.f;

  // Q fragments in registers (wave's 16 rows)
  const int tq = t0 + 16 * wv + l15;
  half8 qf[8];
  {
    const f16* qrow = mel + ((size_t)b * 2000 + ((tq < 2000) ? tq : 0)) * 256;
#pragma unroll
    for (int c = 0; c < 8; ++c) qf[c] = *(const half8*)(qrow + c * 32 + q * 8);
    if (tq >= 2000) {
      half8 z = {};
#pragma unroll
      for (int c = 0; c < 8; ++c) qf[c] = z;
    }
  }
  // fused copymel: out[..., 0:256] = mel_enc (from qf, f16 -> f32)
  if (tq < 2000) {
    float* orow = out + ((size_t)b * 2000 + tq) * 512;
#pragma unroll
    for (int c = 0; c < 8; ++c) {
      half8 h = qf[c];
      float4 f0 = {(float)h[0], (float)h[1], (float)h[2], (float)h[3]};
      float4 f1 = {(float)h[4], (float)h[5], (float)h[6], (float)h[7]};
      *(float4*)(orow + c * 32 + q * 8) = f0;
      *(float4*)(orow + c * 32 + q * 8 + 4) = f1;
    }
  }

  half8 vreg[8];
  const int d_st = tid >> 3, v_st = tid & 7;
  auto loadV = [&](int kt) {
#pragma unroll
    for (int it = 0; it < 8; ++it) {
      int d = d_st + 32 * it;
      vreg[it] = *(const half8*)(phT + ((size_t)b * 256 + d) * 576 + kt * 64 + v_st * 8);
    }
  };
  loadV(0);

  float mr[4], lr[4];
#pragma unroll
  for (int r = 0; r < 4; ++r) { mr[r] = -3.0e38f; lr[r] = 0.f; }
  f32x4 acc[16] = {};
  f16* pw = ps[wv];

#pragma unroll 1
  for (int kt = 0; kt < 9; ++kt) {
    const int s0 = kt * 64;
    __syncthreads();  // prev iter's PV reads of vt done (kt=0: phs ready too)
#pragma unroll
    for (int it = 0; it < 8; ++it)
      *(half8*)(vt + (d_st + 32 * it) * 72 + v_st * 8) = vreg[it];
    __syncthreads();  // vt ready
    if (kt < 8) loadV(kt + 1);  // in flight during compute

    // QK^T: B-frags direct from global (identical across waves -> L1 hits)
    const f16* krow[4];
#pragma unroll
    for (int cf = 0; cf < 4; ++cf)
      krow[cf] = ph + ((size_t)b * 513 + (s0 + cf * 16 + l15)) * 256 + q * 8;
    f32x4 sc[4] = {};
    __builtin_amdgcn_s_setprio(1);
#pragma unroll
    for (int c = 0; c < 8; ++c) {
#pragma unroll
      for (int cf = 0; cf < 4; ++cf) {
        half8 bf = *(const half8*)(krow[cf] + c * 32);
        sc[cf] = mfma16(qf[c], bf, sc[cf]);
      }
    }
    __builtin_amdgcn_s_setprio(0);
    // score epilogue + online softmax (reduce across 16-lane quads)
    float p[4][4];
    float rmax[4] = {-3.0e38f, -3.0e38f, -3.0e38f, -3.0e38f};
#pragma unroll
    for (int cf = 0; cf < 4; ++cf) {
      int sloc = cf * 16 + l15;
      int s = s0 + sloc;
      bool msk = (s > plen) || (s >= 513);
      float p2 = phs[s0 + sloc];
#pragma unroll
      for (int r = 0; r < 4; ++r) {
        float v = 2.0f * sc[cf][r] - p2;
        if (msk) v = -1.0e9f;
        p[cf][r] = v;
        rmax[r] = fmaxf(rmax[r], v);
      }
    }
#pragma unroll
    for (int r = 0; r < 4; ++r)
#pragma unroll
      for (int off = 1; off < 16; off <<= 1)
        rmax[r] = fmaxf(rmax[r], __shfl_xor(rmax[r], off));
    float alpha[4];
#pragma unroll
    for (int r = 0; r < 4; ++r) {
      float mn = fmaxf(mr[r], rmax[r]);
      alpha[r] = __expf(mr[r] - mn);
      mr[r] = mn;
      float rs = 0.f;
#pragma unroll
      for (int cf = 0; cf < 4; ++cf) {
        float e = __expf(p[cf][r] - mn);
        p[cf][r] = e;
        rs += e;
      }
#pragma unroll
      for (int off = 1; off < 16; off <<= 1) rs += __shfl_xor(rs, off);
      lr[r] = lr[r] * alpha[r] + rs;
    }
#pragma unroll
    for (int dt = 0; dt < 16; ++dt)
#pragma unroll
      for (int r = 0; r < 4; ++r) acc[dt][r] *= alpha[r];
    // P to wave-private LDS (C-layout), read back in A-layout (no barrier:
    // wave-private region, lgkmcnt orders the ds ops within the wave)
#pragma unroll
    for (int cf = 0; cf < 4; ++cf)
#pragma unroll
      for (int r = 0; r < 4; ++r)
        pw[(q * 4 + r) * 72 + cf * 16 + l15] = (f16)p[cf][r];
    // PV: 16 t-rows x 256 d-cols, K = 64 (2 chunks), V from LDS
#pragma unroll
    for (int kc = 0; kc < 2; ++kc) {
      half8 pa = *(const half8*)(pw + l15 * 72 + kc * 32 + q * 8);
      __builtin_amdgcn_s_setprio(1);
#pragma unroll
      for (int dt = 0; dt < 16; ++dt) {
        half8 vb = *(const half8*)(vt + (dt * 16 + l15) * 72 + kc * 32 + q * 8);
        acc[dt] = mfma16(pa, vb, acc[dt]);
      }
      __builtin_amdgcn_s_setprio(0);
    }
  }
  float inv[4];
#pragma unroll
  for (int r = 0; r < 4; ++r) inv[r] = 1.0f / lr[r];
#pragma unroll
  for (int dt = 0; dt < 16; ++dt)
#pragma unroll
    for (int r = 0; r < 4; ++r) {
      int t = t0 + 16 * wv + q * 4 + r;
      if (t < 2000) {
        int d = dt * 16 + l15;
        out[((size_t)b * 2000 + t) * 512 + 256 + d] = acc[dt][r] * inv[r];
      }
    }
}

extern "C" void kernel_launch(void* const* d_in, const int* in_sizes, int n_in,
                              void* d_out, int out_size, void* d_ws, size_t ws_size,
                              hipStream_t stream) {
  (void)in_sizes; (void)n_in; (void)out_size; (void)ws_size;
  const float* mels       = (const float*)d_in[0];
  const int*   phonemes   = (const int*)d_in[1];
  const int*   mel_lens   = (const int*)d_in[2];
  const int*   ph_lens    = (const int*)d_in[3];
  const float* embedding  = (const float*)d_in[4];
  const float* mel_conv_w = (const float*)d_in[5];
  const float* mel_conv_b = (const float*)d_in[6];
  const float* ph_w       = (const float*)d_in[7];
  const float* ph_b       = (const float*)d_in[8];
  const float* mel_w      = (const float*)d_in[9];
  const float* mel_b      = (const float*)d_in[10];
  float* out = (float*)d_out;

  char* wsp = (char*)d_ws;
  size_t off = 0;
  auto alloc = [&](size_t bytes) -> void* {
    void* p = wsp + off;
    off = (off + bytes + 255) & ~(size_t)255;
    return p;
  };
  // NOTE: p0 must NOT be the last allocation — flash reads up to 63 rows past
  // its end (masked columns). p1/m0 follow it -> in-workspace, safe. GLU also
  // reads 1 row before/after its x buffer (taps) -> in-workspace, masked.
  // p1 is now a REAL buffer (not aliased to m1): fused GLU runs mel and ph
  // layers concurrently, so m1 is live while the ph ping buffer is written.
  // phT still aliases m1 (transpose runs after the last fused layer, whose
  // mel output is m0).
  f16* wtg    = (f16*)alloc(8ull * 512 * 768 * 2);
  f16* wt0    = (f16*)alloc(256ull * 288 * 2);
  float* phsq = (float*)alloc(16416ull * 4);
  f16* p0     = (f16*)alloc(32ull * 513 * 256 * 2);
  f16* p1     = (f16*)alloc(32ull * 513 * 256 * 2);
  f16* m0     = (f16*)alloc(32ull * 2000 * 256 * 2);
  f16* m1     = (f16*)alloc(32ull * 2000 * 256 * 2);
  f16* phT = m1;        // 9.4 MB <= 32.8 MB, used after GLUs done

  prep_wtglu_kernel<<<4096, 256, 0, stream>>>(mel_w, ph_w, wtg);
  prep_wt0_kernel<<<288, 256, 0, stream>>>(mel_conv_w, wt0);
  embed_kernel<<<dim3(513, 32), 64, 0, stream>>>(phonemes, embedding, p0);
  conv0_kernel<<<dim3(32, 4, 32), 256, 0, stream>>>(mels, wt0, mel_conv_b, m0);

  const size_t WL = 512ull * 768;
  // fused GLU layers: mel layer i (mask: t >= mel_lens[b]) + ph layer i
  // (mask: s > phoneme_lens[b]) in one dispatch; ph blocks backfill the tail.
  // Only the last layer writes the masked-region constant.
  glu_fused_kernel<<<2688, 256, 0, stream>>>(
      m0, wtg + 0 * WL, mel_b + 0 * 512, m1, mel_lens,
      p0, wtg + 4 * WL, ph_b + 0 * 512, p1, ph_lens, 0);
  glu_fused_kernel<<<2688, 256, 0, stream>>>(
      m1, wtg + 1 * WL, mel_b + 1 * 512, m0, mel_lens,
      p1, wtg + 5 * WL, ph_b + 1 * 512, p0, ph_lens, 0);
  glu_fused_kernel<<<2688, 256, 0, stream>>>(
      m0, wtg + 2 * WL, mel_b + 2 * 512, m1, mel_lens,
      p0, wtg + 6 * WL, ph_b + 2 * 512, p1, ph_lens, 0);
  glu_fused_kernel<<<2688, 256, 0, stream>>>(
      m1, wtg + 3 * WL, mel_b + 3 * 512, m0, mel_lens,
      p1, wtg + 7 * WL, ph_b + 3 * 512, p0, ph_lens, 1);

  transpose_kernel<<<dim3(9, 4, 32), 256, 0, stream>>>(p0, phT);
  sqnorm_kernel<<<4104, 256, 0, stream>>>(p0, phsq, 16416);
  flash_kernel<<<dim3(32 * 32), 256, 0, stream>>>(m0, p0, phT, phsq, ph_lens, out);
}

// Round 10
// 658.236 us; speedup vs baseline: 1.6734x; 1.0353x over previous
//
#include <hip/hip_runtime.h>

typedef _Float16 f16;
typedef __attribute__((ext_vector_type(8))) _Float16 half8;
typedef __attribute__((ext_vector_type(4))) _Float16 half4;
typedef __attribute__((ext_vector_type(4))) float f32x4;

__device__ inline f32x4 mfma16(half8 a, half8 b, f32x4 c) {
  return __builtin_amdgcn_mfma_f32_16x16x32_f16(a, b, c, 0, 0, 0);
}

// ---------------- weight prep ----------------
// GLU weights: Wt[l][r][tap*256+i] (f16), rows reordered so each 32-row group
// is 16 a-channels then 16 g-channels. One block per (l,r) row.
__global__ void prep_wtglu_kernel(const float* __restrict__ mel_w,
                                  const float* __restrict__ ph_w,
                                  f16* __restrict__ wt) {
  int bid = blockIdx.x;          // l*512 + r
  int l = bid >> 9, r = bid & 511;
  int tid = threadIdx.x;         // 0..255 = input channel i
  int n32 = r >> 5, j = r & 31;
  int ch = (j < 16) ? (n32 * 16 + j) : (256 + n32 * 16 + (j - 16));
  const float* src = ((l < 4) ? (mel_w + (size_t)l * 512 * 256 * 3)
                              : (ph_w + (size_t)(l - 4) * 512 * 256 * 3)) +
                     (size_t)ch * 768;
  f16* dst = wt + (size_t)bid * 768;
  float a0 = src[tid * 3], a1 = src[tid * 3 + 1], a2 = src[tid * 3 + 2];
  dst[tid] = (f16)a0;
  dst[256 + tid] = (f16)a1;
  dst[512 + tid] = (f16)a2;
}

// mel conv0 weights: Wt0[o][tap*96+i] (f16), channels padded 80->96 with zeros.
__global__ void prep_wt0_kernel(const float* __restrict__ w, f16* __restrict__ wt0) {
  int idx = blockIdx.x * 256 + threadIdx.x;
  const int total = 256 * 288;
  if (idx >= total) return;
  int o = idx / 288, k = idx % 288;
  int tap = k / 96, i = k % 96;
  wt0[idx] = (i < 80) ? (f16)w[((size_t)o * 80 + i) * 3 + tap] : (f16)0.f;
}

// ---------------- embedding (with blank prepend), f32 -> f16 ----------------
__global__ void embed_kernel(const int* __restrict__ phon, const float* __restrict__ emb,
                             f16* __restrict__ out) {
  int s = blockIdx.x, b = blockIdx.y;
  int lane = threadIdx.x;
  int tok = (s == 0) ? 0 : phon[b * 512 + (s - 1)];
  float4 f = *(const float4*)(emb + (size_t)tok * 256 + lane * 4);
  half4 h = {(f16)f.x, (f16)f.y, (f16)f.z, (f16)f.w};
  *(half4*)(out + ((size_t)b * 513 + s) * 256 + lane * 4) = h;
}

// ---------------- mel conv0 (K = 3 taps x 96 padded ch) ----------------
__global__ __launch_bounds__(256) void conv0_kernel(
    const float* __restrict__ mels, const f16* __restrict__ wt0,
    const float* __restrict__ bias, f16* __restrict__ out) {
  __shared__ f16 xs[66 * 104];
  __shared__ f16 ws[64 * 104];
  const int tid = threadIdx.x;
  const int b = blockIdx.z;
  const int t0 = blockIdx.x * 64;
  const int by = blockIdx.y;  // 0..3 (64 out-ch each)

  for (int idx = tid; idx < 66 * 24; idx += 256) {
    int r = idx / 24, v = idx % 24;
    int t = t0 - 1 + r;
    half4 h = {0.f, 0.f, 0.f, 0.f};
    if (t >= 0 && t < 2000 && v < 20) {
      float4 f = *(const float4*)(mels + ((size_t)b * 2000 + t) * 80 + v * 4);
      h[0] = (f16)f.x; h[1] = (f16)f.y; h[2] = (f16)f.z; h[3] = (f16)f.w;
    }
    *(half4*)(xs + r * 104 + v * 4) = h;
  }
  const int lane = tid & 63, wv = tid >> 6;
  const int wr = wv >> 1, wc = wv & 1;
  const int l15 = lane & 15, q = lane >> 4;
  f32x4 acc[2][2] = {};
  const f16* wrow = wt0 + (size_t)(by * 64) * 288;
  for (int tap = 0; tap < 3; ++tap) {
    __syncthreads();
    for (int idx = tid; idx < 64 * 12; idx += 256) {
      int r = idx / 12, v = idx % 12;
      *(half8*)(ws + r * 104 + v * 8) =
          *(const half8*)(wrow + (size_t)r * 288 + tap * 96 + v * 8);
    }
    __syncthreads();
#pragma unroll
    for (int s2 = 0; s2 < 3; ++s2) {
      int ch = s2 * 32 + q * 8;
      half8 a0 = *(const half8*)(xs + (32 * wr + l15 + tap) * 104 + ch);
      half8 a1 = *(const half8*)(xs + (32 * wr + 16 + l15 + tap) * 104 + ch);
      half8 b0 = *(const half8*)(ws + (32 * wc + l15) * 104 + ch);
      half8 b1 = *(const half8*)(ws + (32 * wc + 16 + l15) * 104 + ch);
      acc[0][0] = mfma16(a0, b0, acc[0][0]);
      acc[0][1] = mfma16(a0, b1, acc[0][1]);
      acc[1][0] = mfma16(a1, b0, acc[1][0]);
      acc[1][1] = mfma16(a1, b1, acc[1][1]);
    }
  }
#pragma unroll
  for (int rf = 0; rf < 2; ++rf)
#pragma unroll
    for (int cf = 0; cf < 2; ++cf) {
      int c = by * 64 + 32 * wc + 16 * cf + l15;
      float bb = bias[c];
#pragma unroll
      for (int r = 0; r < 4; ++r) {
        int t = t0 + 32 * wr + 16 * rf + 4 * q + r;
        if (t < 2000)
          out[((size_t)b * 2000 + t) * 256 + c] = (f16)(acc[rf][cf][r] + bb);
      }
    }
}

// ---------------- GLU v9 body: v8 structure, callable for mel or ph part ----
// 128t x 128n block, X staged once per cb (12 phases, taps read row-shifted),
// W reg-prefetch dbuf, per-batch t-tile rotation, masked-block early-out.
__device__ __forceinline__ void glu_body(
    f16* xs, f16* ws2,
    const f16* __restrict__ x, const f16* __restrict__ wt,
    const float* __restrict__ bias, f16* __restrict__ out,
    const int* __restrict__ lens, int lenAdd, int T, int TT, int writeConst,
    int bx, int by, int b) {
  const int tid = threadIdx.x;
  const int tt = (bx + b) % TT;   // per-batch rotation (bijective)
  const int t0 = tt * 128;
  int thr = lens[b] + lenAdd;
  if (thr > T) thr = T;
  const size_t xbase = (size_t)b * T * 256;
  const int lane = tid & 63, wv = tid >> 6;
  const int wr = wv >> 1, wc = wv & 1;   // wave tile 64t x 64n
  const int l15 = lane & 15, q = lane >> 4;

  if (t0 > thr) {
    // all conv inputs masked-zero -> constant output (only final layers write)
    if (writeConst) {
#pragma unroll
      for (int p = 0; p < 2; ++p) {
        int n32 = by * 4 + wc * 2 + p;
        int c = n32 * 16 + l15;
        float ba = bias[c], bg = bias[256 + c];
        f16 o = (f16)((ba * (1.0f / (1.0f + __expf(-bg)))) * 0.70710678118f);
#pragma unroll
        for (int mt = 0; mt < 4; ++mt)
#pragma unroll
          for (int rr = 0; rr < 4; ++rr) {
            int t = t0 + wr * 64 + mt * 16 + q * 4 + rr;
            if (t < T) out[xbase + (size_t)t * 256 + c] = o;
          }
      }
    }
    return;
  }

  f32x4 acc[4][4] = {};
  const f16* wrow = wt + (size_t)(by * 128) * 768;
  const int r_st = tid >> 3, v_st = tid & 7;

  // X stage: 130 rows (t0-1 .. t0+128) x 64 ch = 1040 half8 slots
  half8 xr[5], wreg[4];
  auto loadX = [&](int cb) {
#pragma unroll
    for (int it = 0; it < 5; ++it) {
      int idx = tid + it * 256;
      half8 val = {};
      if (idx < 1040) {
        int lr = idx >> 3, v = idx & 7;
        int trow = t0 - 1 + lr;
        if (trow >= 0 && trow < thr)
          val = *(const half8*)(x + xbase + (size_t)trow * 256 + cb * 64 + v * 8);
      }
      xr[it] = val;
    }
  };
  auto storeX = [&]() {
#pragma unroll
    for (int it = 0; it < 5; ++it) {
      int idx = tid + it * 256;
      if (idx < 1040) {
        int lr = idx >> 3, v = idx & 7;
        *(half8*)(xs + lr * 72 + v * 8) = xr[it];
      }
    }
  };
  auto loadW = [&](int tap, int cb) {
#pragma unroll
    for (int it = 0; it < 4; ++it) {
      int r = r_st + 32 * it;
      wreg[it] = *(const half8*)(wrow + (size_t)r * 768 + tap * 256 + cb * 64 + v_st * 8);
    }
  };
  auto storeW = [&]() {
#pragma unroll
    for (int it = 0; it < 4; ++it)
      *(half8*)(ws2 + (r_st + 32 * it) * 72 + v_st * 8) = wreg[it];
  };

  loadX(0);
  loadW(0, 0);

  for (int p = 0; p < 12; ++p) {
    const int cb = p / 3, tap = p - cb * 3;
    __syncthreads();   // previous phase's LDS reads done
    if (tap == 0) storeX();
    storeW();
    __syncthreads();   // LDS ready
    if (p < 11) {      // prefetch next phase (in flight during MFMA)
      int np = p + 1, ncb = np / 3, ntap = np - ncb * 3;
      if (ntap == 0) loadX(ncb);
      loadW(ntap, ncb);
    }

    half8 af[4][2];
#pragma unroll
    for (int mt = 0; mt < 4; ++mt)
#pragma unroll
      for (int kc = 0; kc < 2; ++kc)
        af[mt][kc] = *(const half8*)(xs + (wr * 64 + mt * 16 + l15 + tap) * 72 + kc * 32 + q * 8);
#pragma unroll
    for (int nt = 0; nt < 4; ++nt) {
      half8 b0 = *(const half8*)(ws2 + (wc * 64 + nt * 16 + l15) * 72 + q * 8);
      half8 b1 = *(const half8*)(ws2 + (wc * 64 + nt * 16 + l15) * 72 + 32 + q * 8);
#pragma unroll
      for (int mt = 0; mt < 4; ++mt) {
        acc[mt][nt] = mfma16(af[mt][0], b0, acc[mt][nt]);
        acc[mt][nt] = mfma16(af[mt][1], b1, acc[mt][nt]);
      }
    }
  }

  // epilogue: nt pairs (0,1),(2,3) are (a,g) channel groups (rows reordered)
#pragma unroll
  for (int p = 0; p < 2; ++p) {
    int n32 = by * 4 + wc * 2 + p;
    int c = n32 * 16 + l15;
    float ba = bias[c], bg = bias[256 + c];
#pragma unroll
    for (int mt = 0; mt < 4; ++mt) {
#pragma unroll
      for (int rr = 0; rr < 4; ++rr) {
        int t = t0 + wr * 64 + mt * 16 + q * 4 + rr;
        if (t < T && (writeConst || t < thr)) {
          float a = acc[mt][2 * p][rr] + ba;
          float g = acc[mt][2 * p + 1][rr] + bg;
          float xm = (t < thr) ? (float)x[xbase + (size_t)t * 256 + c] : 0.f;
          float o = (a * (1.0f / (1.0f + __expf(-g))) + xm) * 0.70710678118f;
          out[xbase + (size_t)t * 256 + c] = (f16)o;
        }
      }
    }
  }
}

// ---------------- fused GLU layer: mel part (2048 blocks) + ph part (640) ----
// The mel and phoneme encoder chains are independent until the flash kernel;
// fusing layer i of both into one dispatch lets the small ph blocks (launched
// last) backfill the mel dispatch's drain tail instead of serializing.
__global__ __launch_bounds__(256) void glu_fused_kernel(
    const f16* __restrict__ xm, const f16* __restrict__ wtm,
    const float* __restrict__ bm, f16* __restrict__ om,
    const int* __restrict__ mlens,
    const f16* __restrict__ xp, const f16* __restrict__ wtp,
    const float* __restrict__ bp, f16* __restrict__ op,
    const int* __restrict__ plens, int writeConst) {
  __shared__ f16 xs[132 * 72];
  __shared__ f16 ws2[128 * 72];
  const int lin = blockIdx.x;
  if (lin < 2048) {           // mel: 32b x 4y x 16x
    int b = lin >> 6, y = (lin >> 4) & 3, x = lin & 15;
    glu_body(xs, ws2, xm, wtm, bm, om, mlens, 0, 2000, 16, writeConst, x, y, b);
  } else {                    // ph: 32b x 4y x 5x
    int l2 = lin - 2048;
    int b = l2 / 20, r = l2 % 20, y = r / 5, x = r % 5;
    glu_body(xs, ws2, xp, wtp, bp, op, plens, 1, 513, 5, writeConst, x, y, b);
  }
}

// ---------------- transpose ph_enc -> phT [b][256 d][576 s] (zeros padded) ----------------
__global__ __launch_bounds__(256) void transpose_kernel(const f16* __restrict__ ph,
                                                        f16* __restrict__ phT) {
  __shared__ f16 tile[64 * 72];
  const int tid = threadIdx.x;
  const int b = blockIdx.z, s0 = blockIdx.x * 64, d0 = blockIdx.y * 64;
#pragma unroll
  for (int it = 0; it < 2; ++it) {
    int idx = tid + it * 256;
    int r = idx >> 3, v = idx & 7;
    int s = s0 + r;
    half8 val = {};
    if (s < 513) val = *(const half8*)(ph + ((size_t)b * 513 + s) * 256 + d0 + v * 8);
    *(half8*)(tile + r * 72 + v * 8) = val;
  }
  __syncthreads();
#pragma unroll
  for (int it = 0; it < 2; ++it) {
    int idx = tid + it * 256;
    int r = idx >> 3, v = idx & 7;   // r = local d, v*8+j = local s
    half8 val;
#pragma unroll
    for (int j2 = 0; j2 < 8; ++j2) val[j2] = tile[(v * 8 + j2) * 72 + r];
    *(half8*)(phT + ((size_t)b * 256 + d0 + r) * 576 + s0 + v * 8) = val;
  }
}

// ---------------- squared norms (phoneme side; mel_sq cancels in softmax) ----------------
__global__ void sqnorm_kernel(const f16* __restrict__ x, float* __restrict__ sq, int nrows) {
  int row = blockIdx.x * 4 + (threadIdx.x >> 6);
  int lane = threadIdx.x & 63;
  if (row >= nrows) return;
  const f16* p = x + (size_t)row * 256;
  float v = 0.f;
  for (int i = lane; i < 256; i += 64) { float f = (float)p[i]; v += f * f; }
  for (int off = 32; off > 0; off >>= 1) v += __shfl_down(v, off);
  if (lane == 0) sq[row] = v;
}

// ---------------- fused dist+softmax+context + mel copy (flash-style) ----------------
// v10 = v7 + masked-tile early-exit: kt tiles with s0 > plen are fully masked
// (p = exp(-1e9 - m) = 0 -> no effect on mr/lr/acc), so the loop runs only
// nkt = ceil((plen+1)/64) of 9 tiles (mean ~4.5). Numerically exact.
// v7 base: V^T reg-prefetch -> LDS vt, 2 barriers/kt, K direct from global,
// XCD-bijective swizzle (4 batches/XCD -> K/V L2-resident), setprio on MFMA.
// scores(t,s) = 2*dot(mel_t, ph_s) - |ph_s|^2  (row-constant -|mel_t|^2 dropped).
// K reads for s in [513,576) hit in-workspace garbage but are masked pre-max.
__global__ __launch_bounds__(256) void flash_kernel(
    const f16* __restrict__ mel, const f16* __restrict__ ph,
    const f16* __restrict__ phT, const float* __restrict__ phsq,
    const int* __restrict__ plens, float* __restrict__ out) {
  __shared__ f16 vt[256 * 72];   // V^T tile [d][s-local]
  __shared__ f16 ps[4][16 * 72]; // per-wave P 16x64 (wave-private)
  __shared__ float phs[576];
  const int tid = threadIdx.x;
  // XCD swizzle (bijective): b = (lin>>8)*8 + (lin&7), tt = (lin>>3)&31.
  const int lin = blockIdx.x;
  const int b = ((lin >> 8) << 3) | (lin & 7);
  const int t0 = ((lin >> 3) & 31) * 64;
  const int lane = tid & 63, wv = tid >> 6;
  const int l15 = lane & 15, q = lane >> 4;
  const int plen = plens[b];
  const int nkt = (plen + 64) >> 6;   // ceil((plen+1)/64), in [1,9]

  for (int idx = tid; idx < 576; idx += 256)
    phs[idx] = (idx < 513) ? phsq[b * 513 + idx] : 0.f;

  // Q fragments in registers (wave's 16 rows)
  const int tq = t0 + 16 * wv + l15;
  half8 qf[8];
  {
    const f16* qrow = mel + ((size_t)b * 2000 + ((tq < 2000) ? tq : 0)) * 256;
#pragma unroll
    for (int c = 0; c < 8; ++c) qf[c] = *(const half8*)(qrow + c * 32 + q * 8);
    if (tq >= 2000) {
      half8 z = {};
#pragma unroll
      for (int c = 0; c < 8; ++c) qf[c] = z;
    }
  }
  // fused copymel: out[..., 0:256] = mel_enc (from qf, f16 -> f32)
  if (tq < 2000) {
    float* orow = out + ((size_t)b * 2000 + tq) * 512;
#pragma unroll
    for (int c = 0; c < 8; ++c) {
      half8 h = qf[c];
      float4 f0 = {(float)h[0], (float)h[1], (float)h[2], (float)h[3]};
      float4 f1 = {(float)h[4], (float)h[5], (float)h[6], (float)h[7]};
      *(float4*)(orow + c * 32 + q * 8) = f0;
      *(float4*)(orow + c * 32 + q * 8 + 4) = f1;
    }
  }

  half8 vreg[8];
  const int d_st = tid >> 3, v_st = tid & 7;
  auto loadV = [&](int kt) {
#pragma unroll
    for (int it = 0; it < 8; ++it) {
      int d = d_st + 32 * it;
      vreg[it] = *(const half8*)(phT + ((size_t)b * 256 + d) * 576 + kt * 64 + v_st * 8);
    }
  };
  loadV(0);

  float mr[4], lr[4];
#pragma unroll
  for (int r = 0; r < 4; ++r) { mr[r] = -3.0e38f; lr[r] = 0.f; }
  f32x4 acc[16] = {};
  f16* pw = ps[wv];

#pragma unroll 1
  for (int kt = 0; kt < nkt; ++kt) {
    const int s0 = kt * 64;
    __syncthreads();  // prev iter's PV reads of vt done (kt=0: phs ready too)
#pragma unroll
    for (int it = 0; it < 8; ++it)
      *(half8*)(vt + (d_st + 32 * it) * 72 + v_st * 8) = vreg[it];
    __syncthreads();  // vt ready
    if (kt + 1 < nkt) loadV(kt + 1);  // in flight during compute

    // QK^T: B-frags direct from global (identical across waves -> L1 hits)
    const f16* krow[4];
#pragma unroll
    for (int cf = 0; cf < 4; ++cf)
      krow[cf] = ph + ((size_t)b * 513 + (s0 + cf * 16 + l15)) * 256 + q * 8;
    f32x4 sc[4] = {};
    __builtin_amdgcn_s_setprio(1);
#pragma unroll
    for (int c = 0; c < 8; ++c) {
#pragma unroll
      for (int cf = 0; cf < 4; ++cf) {
        half8 bf = *(const half8*)(krow[cf] + c * 32);
        sc[cf] = mfma16(qf[c], bf, sc[cf]);
      }
    }
    __builtin_amdgcn_s_setprio(0);
    // score epilogue + online softmax (reduce across 16-lane quads)
    float p[4][4];
    float rmax[4] = {-3.0e38f, -3.0e38f, -3.0e38f, -3.0e38f};
#pragma unroll
    for (int cf = 0; cf < 4; ++cf) {
      int sloc = cf * 16 + l15;
      int s = s0 + sloc;
      bool msk = (s > plen) || (s >= 513);
      float p2 = phs[s0 + sloc];
#pragma unroll
      for (int r = 0; r < 4; ++r) {
        float v = 2.0f * sc[cf][r] - p2;
        if (msk) v = -1.0e9f;
        p[cf][r] = v;
        rmax[r] = fmaxf(rmax[r], v);
      }
    }
#pragma unroll
    for (int r = 0; r < 4; ++r)
#pragma unroll
      for (int off = 1; off < 16; off <<= 1)
        rmax[r] = fmaxf(rmax[r], __shfl_xor(rmax[r], off));
    float alpha[4];
#pragma unroll
    for (int r = 0; r < 4; ++r) {
      float mn = fmaxf(mr[r], rmax[r]);
      alpha[r] = __expf(mr[r] - mn);
      mr[r] = mn;
      float rs = 0.f;
#pragma unroll
      for (int cf = 0; cf < 4; ++cf) {
        float e = __expf(p[cf][r] - mn);
        p[cf][r] = e;
        rs += e;
      }
#pragma unroll
      for (int off = 1; off < 16; off <<= 1) rs += __shfl_xor(rs, off);
      lr[r] = lr[r] * alpha[r] + rs;
    }
#pragma unroll
    for (int dt = 0; dt < 16; ++dt)
#pragma unroll
      for (int r = 0; r < 4; ++r) acc[dt][r] *= alpha[r];
    // P to wave-private LDS (C-layout), read back in A-layout (no barrier:
    // wave-private region, lgkmcnt orders the ds ops within the wave)
#pragma unroll
    for (int cf = 0; cf < 4; ++cf)
#pragma unroll
      for (int r = 0; r < 4; ++r)
        pw[(q * 4 + r) * 72 + cf * 16 + l15] = (f16)p[cf][r];
    // PV: 16 t-rows x 256 d-cols, K = 64 (2 chunks), V from LDS
#pragma unroll
    for (int kc = 0; kc < 2; ++kc) {
      half8 pa = *(const half8*)(pw + l15 * 72 + kc * 32 + q * 8);
      __builtin_amdgcn_s_setprio(1);
#pragma unroll
      for (int dt = 0; dt < 16; ++dt) {
        half8 vb = *(const half8*)(vt + (dt * 16 + l15) * 72 + kc * 32 + q * 8);
        acc[dt] = mfma16(pa, vb, acc[dt]);
      }
      __builtin_amdgcn_s_setprio(0);
    }
  }
  float inv[4];
#pragma unroll
  for (int r = 0; r < 4; ++r) inv[r] = 1.0f / lr[r];
#pragma unroll
  for (int dt = 0; dt < 16; ++dt)
#pragma unroll
    for (int r = 0; r < 4; ++r) {
      int t = t0 + 16 * wv + q * 4 + r;
      if (t < 2000) {
        int d = dt * 16 + l15;
        out[((size_t)b * 2000 + t) * 512 + 256 + d] = acc[dt][r] * inv[r];
      }
    }
}

extern "C" void kernel_launch(void* const* d_in, const int* in_sizes, int n_in,
                              void* d_out, int out_size, void* d_ws, size_t ws_size,
                              hipStream_t stream) {
  (void)in_sizes; (void)n_in; (void)out_size; (void)ws_size;
  const float* mels       = (const float*)d_in[0];
  const int*   phonemes   = (const int*)d_in[1];
  const int*   mel_lens   = (const int*)d_in[2];
  const int*   ph_lens    = (const int*)d_in[3];
  const float* embedding  = (const float*)d_in[4];
  const float* mel_conv_w = (const float*)d_in[5];
  const float* mel_conv_b = (const float*)d_in[6];
  const float* ph_w       = (const float*)d_in[7];
  const float* ph_b       = (const float*)d_in[8];
  const float* mel_w      = (const float*)d_in[9];
  const float* mel_b      = (const float*)d_in[10];
  float* out = (float*)d_out;

  char* wsp = (char*)d_ws;
  size_t off = 0;
  auto alloc = [&](size_t bytes) -> void* {
    void* p = wsp + off;
    off = (off + bytes + 255) & ~(size_t)255;
    return p;
  };
  // NOTE: p0 must NOT be the last allocation — flash reads up to 63 rows past
  // its end (masked columns). p1/m0 follow it -> in-workspace, safe. GLU also
  // reads 1 row before/after its x buffer (taps) -> in-workspace, masked.
  // p1 is a REAL buffer (not aliased to m1): fused GLU runs mel and ph
  // layers concurrently, so m1 is live while the ph ping buffer is written.
  // phT still aliases m1 (transpose runs after the last fused layer, whose
  // mel output is m0).
  f16* wtg    = (f16*)alloc(8ull * 512 * 768 * 2);
  f16* wt0    = (f16*)alloc(256ull * 288 * 2);
  float* phsq = (float*)alloc(16416ull * 4);
  f16* p0     = (f16*)alloc(32ull * 513 * 256 * 2);
  f16* p1     = (f16*)alloc(32ull * 513 * 256 * 2);
  f16* m0     = (f16*)alloc(32ull * 2000 * 256 * 2);
  f16* m1     = (f16*)alloc(32ull * 2000 * 256 * 2);
  f16* phT = m1;        // 9.4 MB <= 32.8 MB, used after GLUs done

  prep_wtglu_kernel<<<4096, 256, 0, stream>>>(mel_w, ph_w, wtg);
  prep_wt0_kernel<<<288, 256, 0, stream>>>(mel_conv_w, wt0);
  embed_kernel<<<dim3(513, 32), 64, 0, stream>>>(phonemes, embedding, p0);
  conv0_kernel<<<dim3(32, 4, 32), 256, 0, stream>>>(mels, wt0, mel_conv_b, m0);

  const size_t WL = 512ull * 768;
  // fused GLU layers: mel layer i (mask: t >= mel_lens[b]) + ph layer i
  // (mask: s > phoneme_lens[b]) in one dispatch; ph blocks backfill the tail.
  // Only the last layer writes the masked-region constant.
  glu_fused_kernel<<<2688, 256, 0, stream>>>(
      m0, wtg + 0 * WL, mel_b + 0 * 512, m1, mel_lens,
      p0, wtg + 4 * WL, ph_b + 0 * 512, p1, ph_lens, 0);
  glu_fused_kernel<<<2688, 256, 0, stream>>>(
      m1, wtg + 1 * WL, mel_b + 1 * 512, m0, mel_lens,
      p1, wtg + 5 * WL, ph_b + 1 * 512, p0, ph_lens, 0);
  glu_fused_kernel<<<2688, 256, 0, stream>>>(
      m0, wtg + 2 * WL, mel_b + 2 * 512, m1, mel_lens,
      p0, wtg + 6 * WL, ph_b + 2 * 512, p1, ph_lens, 0);
  glu_fused_kernel<<<2688, 256, 0, stream>>>(
      m1, wtg + 3 * WL, mel_b + 3 * 512, m0, mel_lens,
      p1, wtg + 7 * WL, ph_b + 3 * 512, p0, ph_lens, 1);

  transpose_kernel<<<dim3(9, 4, 32), 256, 0, stream>>>(p0, phT);
  sqnorm_kernel<<<4104, 256, 0, stream>>>(p0, phsq, 16416);
  flash_kernel<<<dim3(32 * 32), 256, 0, stream>>>(m0, p0, phT, phsq, ph_lens, out);
}

// Round 11
// 614.494 us; speedup vs baseline: 1.7925x; 1.0712x over previous
//
#include <hip/hip_runtime.h>

typedef _Float16 f16;
typedef __attribute__((ext_vector_type(8))) _Float16 half8;
typedef __attribute__((ext_vector_type(4))) _Float16 half4;
typedef __attribute__((ext_vector_type(4))) float f32x4;

__device__ inline f32x4 mfma16(half8 a, half8 b, f32x4 c) {
  return __builtin_amdgcn_mfma_f32_16x16x32_f16(a, b, c, 0, 0, 0);
}

// ---------------- weight prep ----------------
// GLU weights v2: frag-ordered for direct global->register B-frag loads.
// Layout: [l][by][p][wc][nt][kc][lane][8] (f16), 8192 f16 per (l,by,p).
// Value = w[ch(r_g)][cb*64+kc*32+(lane>>4)*8+e][tap], where r_g = by*128 +
// wc*64 + nt*16 + (lane&15) is the reordered output row (32-row groups of
// 16 a- then 16 g-channels), p = cb*3+tap. Lane q*16+l15 reads its 16B frag
// at base+lane*16 -> perfectly coalesced dwordx4 loads in the GLU kernel.
__global__ void prep_wtglu_kernel(const float* __restrict__ mel_w,
                                  const float* __restrict__ ph_w,
                                  f16* __restrict__ wt) {
  int bid = blockIdx.x;              // (l*4+by)*12 + p ; 384 blocks
  int p = bid % 12, lby = bid / 12;
  int by = lby & 3, l = lby >> 2;
  int cb = p / 3, tap = p - cb * 3;
  const float* src = (l < 4) ? (mel_w + (size_t)l * 512 * 256 * 3)
                             : (ph_w + (size_t)(l - 4) * 512 * 256 * 3);
  f16* dst = wt + (size_t)bid * 8192;
  int tid = threadIdx.x;
#pragma unroll
  for (int k = 0; k < 4; ++k) {
    int s = tid + k * 256;           // slot in [0,1024)
    int lane = s & 63, rest = s >> 6;
    int kc = rest & 1, nt = (rest >> 1) & 3, wc = rest >> 3;
    int rg = by * 128 + wc * 64 + nt * 16 + (lane & 15);
    int n32 = rg >> 5, j = rg & 31;
    int ch = (j < 16) ? (n32 * 16 + j) : (256 + n32 * 16 + (j - 16));
    int i0 = cb * 64 + kc * 32 + (lane >> 4) * 8;
#pragma unroll
    for (int e = 0; e < 8; ++e)
      dst[(size_t)s * 8 + e] = (f16)src[((size_t)ch * 256 + i0 + e) * 3 + tap];
  }
}

// mel conv0 weights: Wt0[o][tap*96+i] (f16), channels padded 80->96 with zeros.
__global__ void prep_wt0_kernel(const float* __restrict__ w, f16* __restrict__ wt0) {
  int idx = blockIdx.x * 256 + threadIdx.x;
  const int total = 256 * 288;
  if (idx >= total) return;
  int o = idx / 288, k = idx % 288;
  int tap = k / 96, i = k % 96;
  wt0[idx] = (i < 80) ? (f16)w[((size_t)o * 80 + i) * 3 + tap] : (f16)0.f;
}

// ---------------- embedding (with blank prepend), f32 -> f16 ----------------
__global__ void embed_kernel(const int* __restrict__ phon, const float* __restrict__ emb,
                             f16* __restrict__ out) {
  int s = blockIdx.x, b = blockIdx.y;
  int lane = threadIdx.x;
  int tok = (s == 0) ? 0 : phon[b * 512 + (s - 1)];
  float4 f = *(const float4*)(emb + (size_t)tok * 256 + lane * 4);
  half4 h = {(f16)f.x, (f16)f.y, (f16)f.z, (f16)f.w};
  *(half4*)(out + ((size_t)b * 513 + s) * 256 + lane * 4) = h;
}

// ---------------- mel conv0 (K = 3 taps x 96 padded ch) ----------------
__global__ __launch_bounds__(256) void conv0_kernel(
    const float* __restrict__ mels, const f16* __restrict__ wt0,
    const float* __restrict__ bias, f16* __restrict__ out) {
  __shared__ f16 xs[66 * 104];
  __shared__ f16 ws[64 * 104];
  const int tid = threadIdx.x;
  const int b = blockIdx.z;
  const int t0 = blockIdx.x * 64;
  const int by = blockIdx.y;  // 0..3 (64 out-ch each)

  for (int idx = tid; idx < 66 * 24; idx += 256) {
    int r = idx / 24, v = idx % 24;
    int t = t0 - 1 + r;
    half4 h = {0.f, 0.f, 0.f, 0.f};
    if (t >= 0 && t < 2000 && v < 20) {
      float4 f = *(const float4*)(mels + ((size_t)b * 2000 + t) * 80 + v * 4);
      h[0] = (f16)f.x; h[1] = (f16)f.y; h[2] = (f16)f.z; h[3] = (f16)f.w;
    }
    *(half4*)(xs + r * 104 + v * 4) = h;
  }
  const int lane = tid & 63, wv = tid >> 6;
  const int wr = wv >> 1, wc = wv & 1;
  const int l15 = lane & 15, q = lane >> 4;
  f32x4 acc[2][2] = {};
  const f16* wrow = wt0 + (size_t)(by * 64) * 288;
  for (int tap = 0; tap < 3; ++tap) {
    __syncthreads();
    for (int idx = tid; idx < 64 * 12; idx += 256) {
      int r = idx / 12, v = idx % 12;
      *(half8*)(ws + r * 104 + v * 8) =
          *(const half8*)(wrow + (size_t)r * 288 + tap * 96 + v * 8);
    }
    __syncthreads();
#pragma unroll
    for (int s2 = 0; s2 < 3; ++s2) {
      int ch = s2 * 32 + q * 8;
      half8 a0 = *(const half8*)(xs + (32 * wr + l15 + tap) * 104 + ch);
      half8 a1 = *(const half8*)(xs + (32 * wr + 16 + l15 + tap) * 104 + ch);
      half8 b0 = *(const half8*)(ws + (32 * wc + l15) * 104 + ch);
      half8 b1 = *(const half8*)(ws + (32 * wc + 16 + l15) * 104 + ch);
      acc[0][0] = mfma16(a0, b0, acc[0][0]);
      acc[0][1] = mfma16(a0, b1, acc[0][1]);
      acc[1][0] = mfma16(a1, b0, acc[1][0]);
      acc[1][1] = mfma16(a1, b1, acc[1][1]);
    }
  }
#pragma unroll
  for (int rf = 0; rf < 2; ++rf)
#pragma unroll
    for (int cf = 0; cf < 2; ++cf) {
      int c = by * 64 + 32 * wc + 16 * cf + l15;
      float bb = bias[c];
#pragma unroll
      for (int r = 0; r < 4; ++r) {
        int t = t0 + 32 * wr + 16 * rf + 4 * q + r;
        if (t < 2000)
          out[((size_t)b * 2000 + t) * 256 + c] = (f16)(acc[rf][cf][r] + bb);
      }
    }
}

// ---------------- GLU v10 body: W direct global->reg (frag-ordered) --------
// X staged in LDS once per cb (4 barrier pairs total, taps read row-shifted);
// W loaded per phase as 8 coalesced dwordx4 into regs, double-buffered one
// phase ahead (v4's proven reg-prefetch, minus the LDS round trip). Per-phase
// LDS ops drop 21 -> 8; barriers 24 -> 8; LDS 37.4 -> 19 KB. Same per-lane W
// values as the LDS path (prep emits frag order). Early-out + rotation as v9.
__device__ __forceinline__ void glu_body(
    f16* xs,
    const f16* __restrict__ x, const f16* __restrict__ wt,
    const float* __restrict__ bias, f16* __restrict__ out,
    const int* __restrict__ lens, int lenAdd, int T, int TT, int writeConst,
    int bx, int by, int b) {
  const int tid = threadIdx.x;
  const int tt = (bx + b) % TT;   // per-batch rotation (bijective)
  const int t0 = tt * 128;
  int thr = lens[b] + lenAdd;
  if (thr > T) thr = T;
  const size_t xbase = (size_t)b * T * 256;
  const int lane = tid & 63, wv = tid >> 6;
  const int wr = wv >> 1, wc = wv & 1;   // wave tile 64t x 64n
  const int l15 = lane & 15, q = lane >> 4;

  if (t0 > thr) {
    // all conv inputs masked-zero -> constant output (only final layers write)
    if (writeConst) {
#pragma unroll
      for (int p = 0; p < 2; ++p) {
        int n32 = by * 4 + wc * 2 + p;
        int c = n32 * 16 + l15;
        float ba = bias[c], bg = bias[256 + c];
        f16 o = (f16)((ba * (1.0f / (1.0f + __expf(-bg)))) * 0.70710678118f);
#pragma unroll
        for (int mt = 0; mt < 4; ++mt)
#pragma unroll
          for (int rr = 0; rr < 4; ++rr) {
            int t = t0 + wr * 64 + mt * 16 + q * 4 + rr;
            if (t < T) out[xbase + (size_t)t * 256 + c] = o;
          }
      }
    }
    return;
  }

  f32x4 acc[4][4] = {};
  const f16* wby = wt + (size_t)by * 12 * 8192 + (size_t)wc * 4096 + (size_t)lane * 8;

  // X stage: 130 rows (t0-1 .. t0+128) x 64 ch = 1040 half8 slots
  half8 xr[5];
  half8 wb[4][2], wn[4][2];
  auto loadX = [&](int cb) {
#pragma unroll
    for (int it = 0; it < 5; ++it) {
      int idx = tid + it * 256;
      half8 val = {};
      if (idx < 1040) {
        int lr = idx >> 3, v = idx & 7;
        int trow = t0 - 1 + lr;
        if (trow >= 0 && trow < thr)
          val = *(const half8*)(x + xbase + (size_t)trow * 256 + cb * 64 + v * 8);
      }
      xr[it] = val;
    }
  };
  auto storeX = [&]() {
#pragma unroll
    for (int it = 0; it < 5; ++it) {
      int idx = tid + it * 256;
      if (idx < 1040) {
        int lr = idx >> 3, v = idx & 7;
        *(half8*)(xs + lr * 72 + v * 8) = xr[it];
      }
    }
  };
  auto loadWreg = [&](half8 W[4][2], int p) {
    const f16* wp = wby + (size_t)p * 8192;
#pragma unroll
    for (int nt = 0; nt < 4; ++nt)
#pragma unroll
      for (int kc = 0; kc < 2; ++kc)
        W[nt][kc] = *(const half8*)(wp + (nt * 2 + kc) * 512);
  };

  loadX(0);
  loadWreg(wb, 0);

#pragma unroll
  for (int cb = 0; cb < 4; ++cb) {
    __syncthreads();   // all waves done reading xs (previous cb's taps)
    storeX();
    __syncthreads();   // xs ready
    if (cb < 3) loadX(cb + 1);   // prefetch next X window during compute
#pragma unroll
    for (int tap = 0; tap < 3; ++tap) {
      const int p = cb * 3 + tap;
      if (p < 11) loadWreg(wn, p + 1);   // W prefetch, in flight during MFMA

      half8 af[4][2];
#pragma unroll
      for (int mt = 0; mt < 4; ++mt)
#pragma unroll
        for (int kc = 0; kc < 2; ++kc)
          af[mt][kc] = *(const half8*)(xs + (wr * 64 + mt * 16 + l15 + tap) * 72 + kc * 32 + q * 8);
      __builtin_amdgcn_s_setprio(1);
#pragma unroll
      for (int nt = 0; nt < 4; ++nt)
#pragma unroll
        for (int mt = 0; mt < 4; ++mt) {
          acc[mt][nt] = mfma16(af[mt][0], wb[nt][0], acc[mt][nt]);
          acc[mt][nt] = mfma16(af[mt][1], wb[nt][1], acc[mt][nt]);
        }
      __builtin_amdgcn_s_setprio(0);
#pragma unroll
      for (int nt = 0; nt < 4; ++nt) {
        wb[nt][0] = wn[nt][0];
        wb[nt][1] = wn[nt][1];
      }
    }
  }

  // epilogue: nt pairs (0,1),(2,3) are (a,g) channel groups (rows reordered)
#pragma unroll
  for (int p = 0; p < 2; ++p) {
    int n32 = by * 4 + wc * 2 + p;
    int c = n32 * 16 + l15;
    float ba = bias[c], bg = bias[256 + c];
#pragma unroll
    for (int mt = 0; mt < 4; ++mt) {
#pragma unroll
      for (int rr = 0; rr < 4; ++rr) {
        int t = t0 + wr * 64 + mt * 16 + q * 4 + rr;
        if (t < T && (writeConst || t < thr)) {
          float a = acc[mt][2 * p][rr] + ba;
          float g = acc[mt][2 * p + 1][rr] + bg;
          float xm = (t < thr) ? (float)x[xbase + (size_t)t * 256 + c] : 0.f;
          float o = (a * (1.0f / (1.0f + __expf(-g))) + xm) * 0.70710678118f;
          out[xbase + (size_t)t * 256 + c] = (f16)o;
        }
      }
    }
  }
}

// ---------------- fused GLU layer: mel part (2048 blocks) + ph part (640) ----
// mel and ph chains are independent until flash; ph blocks (launched last)
// backfill the mel dispatch's drain tail.
__global__ __launch_bounds__(256) void glu_fused_kernel(
    const f16* __restrict__ xm, const f16* __restrict__ wtm,
    const float* __restrict__ bm, f16* __restrict__ om,
    const int* __restrict__ mlens,
    const f16* __restrict__ xp, const f16* __restrict__ wtp,
    const float* __restrict__ bp, f16* __restrict__ op,
    const int* __restrict__ plens, int writeConst) {
  __shared__ f16 xs[132 * 72];
  const int lin = blockIdx.x;
  if (lin < 2048) {           // mel: 32b x 4y x 16x
    int b = lin >> 6, y = (lin >> 4) & 3, x = lin & 15;
    glu_body(xs, xm, wtm, bm, om, mlens, 0, 2000, 16, writeConst, x, y, b);
  } else {                    // ph: 32b x 4y x 5x
    int l2 = lin - 2048;
    int b = l2 / 20, r = l2 % 20, y = r / 5, x = r % 5;
    glu_body(xs, xp, wtp, bp, op, plens, 1, 513, 5, writeConst, x, y, b);
  }
}

// ---------------- transpose ph_enc -> phT [b][256 d][576 s] (zeros padded) ----------------
__global__ __launch_bounds__(256) void transpose_kernel(const f16* __restrict__ ph,
                                                        f16* __restrict__ phT) {
  __shared__ f16 tile[64 * 72];
  const int tid = threadIdx.x;
  const int b = blockIdx.z, s0 = blockIdx.x * 64, d0 = blockIdx.y * 64;
#pragma unroll
  for (int it = 0; it < 2; ++it) {
    int idx = tid + it * 256;
    int r = idx >> 3, v = idx & 7;
    int s = s0 + r;
    half8 val = {};
    if (s < 513) val = *(const half8*)(ph + ((size_t)b * 513 + s) * 256 + d0 + v * 8);
    *(half8*)(tile + r * 72 + v * 8) = val;
  }
  __syncthreads();
#pragma unroll
  for (int it = 0; it < 2; ++it) {
    int idx = tid + it * 256;
    int r = idx >> 3, v = idx & 7;   // r = local d, v*8+j = local s
    half8 val;
#pragma unroll
    for (int j2 = 0; j2 < 8; ++j2) val[j2] = tile[(v * 8 + j2) * 72 + r];
    *(half8*)(phT + ((size_t)b * 256 + d0 + r) * 576 + s0 + v * 8) = val;
  }
}

// ---------------- squared norms (phoneme side; mel_sq cancels in softmax) ----------------
__global__ void sqnorm_kernel(const f16* __restrict__ x, float* __restrict__ sq, int nrows) {
  int row = blockIdx.x * 4 + (threadIdx.x >> 6);
  int lane = threadIdx.x & 63;
  if (row >= nrows) return;
  const f16* p = x + (size_t)row * 256;
  float v = 0.f;
  for (int i = lane; i < 256; i += 64) { float f = (float)p[i]; v += f * f; }
  for (int off = 32; off > 0; off >>= 1) v += __shfl_down(v, off);
  if (lane == 0) sq[row] = v;
}

// ---------------- fused dist+softmax+context + mel copy (flash-style) ----------------
// v10 = v7 + masked-tile early-exit: kt tiles with s0 > plen are fully masked
// (p = exp(-1e9 - m) = 0 -> no effect on mr/lr/acc), so the loop runs only
// nkt = ceil((plen+1)/64) of 9 tiles (mean ~4.5). Numerically exact.
// v7 base: V^T reg-prefetch -> LDS vt, 2 barriers/kt, K direct from global,
// XCD-bijective swizzle (4 batches/XCD -> K/V L2-resident), setprio on MFMA.
// scores(t,s) = 2*dot(mel_t, ph_s) - |ph_s|^2  (row-constant -|mel_t|^2 dropped).
// K reads for s in [513,576) hit in-workspace garbage but are masked pre-max.
__global__ __launch_bounds__(256) void flash_kernel(
    const f16* __restrict__ mel, const f16* __restrict__ ph,
    const f16* __restrict__ phT, const float* __restrict__ phsq,
    const int* __restrict__ plens, float* __restrict__ out) {
  __shared__ f16 vt[256 * 72];   // V^T tile [d][s-local]
  __shared__ f16 ps[4][16 * 72]; // per-wave P 16x64 (wave-private)
  __shared__ float phs[576];
  const int tid = threadIdx.x;
  // XCD swizzle (bijective): b = (lin>>8)*8 + (lin&7), tt = (lin>>3)&31.
  const int lin = blockIdx.x;
  const int b = ((lin >> 8) << 3) | (lin & 7);
  const int t0 = ((lin >> 3) & 31) * 64;
  const int lane = tid & 63, wv = tid >> 6;
  const int l15 = lane & 15, q = lane >> 4;
  const int plen = plens[b];
  const int nkt = (plen + 64) >> 6;   // ceil((plen+1)/64), in [1,9]

  for (int idx = tid; idx < 576; idx += 256)
    phs[idx] = (idx < 513) ? phsq[b * 513 + idx] : 0.f;

  // Q fragments in registers (wave's 16 rows)
  const int tq = t0 + 16 * wv + l15;
  half8 qf[8];
  {
    const f16* qrow = mel + ((size_t)b * 2000 + ((tq < 2000) ? tq : 0)) * 256;
#pragma unroll
    for (int c = 0; c < 8; ++c) qf[c] = *(const half8*)(qrow + c * 32 + q * 8);
    if (tq >= 2000) {
      half8 z = {};
#pragma unroll
      for (int c = 0; c < 8; ++c) qf[c] = z;
    }
  }
  // fused copymel: out[..., 0:256] = mel_enc (from qf, f16 -> f32)
  if (tq < 2000) {
    float* orow = out + ((size_t)b * 2000 + tq) * 512;
#pragma unroll
    for (int c = 0; c < 8; ++c) {
      half8 h = qf[c];
      float4 f0 = {(float)h[0], (float)h[1], (float)h[2], (float)h[3]};
      float4 f1 = {(float)h[4], (float)h[5], (float)h[6], (float)h[7]};
      *(float4*)(orow + c * 32 + q * 8) = f0;
      *(float4*)(orow + c * 32 + q * 8 + 4) = f1;
    }
  }

  half8 vreg[8];
  const int d_st = tid >> 3, v_st = tid & 7;
  auto loadV = [&](int kt) {
#pragma unroll
    for (int it = 0; it < 8; ++it) {
      int d = d_st + 32 * it;
      vreg[it] = *(const half8*)(phT + ((size_t)b * 256 + d) * 576 + kt * 64 + v_st * 8);
    }
  };
  loadV(0);

  float mr[4], lr[4];
#pragma unroll
  for (int r = 0; r < 4; ++r) { mr[r] = -3.0e38f; lr[r] = 0.f; }
  f32x4 acc[16] = {};
  f16* pw = ps[wv];

#pragma unroll 1
  for (int kt = 0; kt < nkt; ++kt) {
    const int s0 = kt * 64;
    __syncthreads();  // prev iter's PV reads of vt done (kt=0: phs ready too)
#pragma unroll
    for (int it = 0; it < 8; ++it)
      *(half8*)(vt + (d_st + 32 * it) * 72 + v_st * 8) = vreg[it];
    __syncthreads();  // vt ready
    if (kt + 1 < nkt) loadV(kt + 1);  // in flight during compute

    // QK^T: B-frags direct from global (identical across waves -> L1 hits)
    const f16* krow[4];
#pragma unroll
    for (int cf = 0; cf < 4; ++cf)
      krow[cf] = ph + ((size_t)b * 513 + (s0 + cf * 16 + l15)) * 256 + q * 8;
    f32x4 sc[4] = {};
    __builtin_amdgcn_s_setprio(1);
#pragma unroll
    for (int c = 0; c < 8; ++c) {
#pragma unroll
      for (int cf = 0; cf < 4; ++cf) {
        half8 bf = *(const half8*)(krow[cf] + c * 32);
        sc[cf] = mfma16(qf[c], bf, sc[cf]);
      }
    }
    __builtin_amdgcn_s_setprio(0);
    // score epilogue + online softmax (reduce across 16-lane quads)
    float p[4][4];
    float rmax[4] = {-3.0e38f, -3.0e38f, -3.0e38f, -3.0e38f};
#pragma unroll
    for (int cf = 0; cf < 4; ++cf) {
      int sloc = cf * 16 + l15;
      int s = s0 + sloc;
      bool msk = (s > plen) || (s >= 513);
      float p2 = phs[s0 + sloc];
#pragma unroll
      for (int r = 0; r < 4; ++r) {
        float v = 2.0f * sc[cf][r] - p2;
        if (msk) v = -1.0e9f;
        p[cf][r] = v;
        rmax[r] = fmaxf(rmax[r], v);
      }
    }
#pragma unroll
    for (int r = 0; r < 4; ++r)
#pragma unroll
      for (int off = 1; off < 16; off <<= 1)
        rmax[r] = fmaxf(rmax[r], __shfl_xor(rmax[r], off));
    float alpha[4];
#pragma unroll
    for (int r = 0; r < 4; ++r) {
      float mn = fmaxf(mr[r], rmax[r]);
      alpha[r] = __expf(mr[r] - mn);
      mr[r] = mn;
      float rs = 0.f;
#pragma unroll
      for (int cf = 0; cf < 4; ++cf) {
        float e = __expf(p[cf][r] - mn);
        p[cf][r] = e;
        rs += e;
      }
#pragma unroll
      for (int off = 1; off < 16; off <<= 1) rs += __shfl_xor(rs, off);
      lr[r] = lr[r] * alpha[r] + rs;
    }
#pragma unroll
    for (int dt = 0; dt < 16; ++dt)
#pragma unroll
      for (int r = 0; r < 4; ++r) acc[dt][r] *= alpha[r];
    // P to wave-private LDS (C-layout), read back in A-layout (no barrier:
    // wave-private region, lgkmcnt orders the ds ops within the wave)
#pragma unroll
    for (int cf = 0; cf < 4; ++cf)
#pragma unroll
      for (int r = 0; r < 4; ++r)
        pw[(q * 4 + r) * 72 + cf * 16 + l15] = (f16)p[cf][r];
    // PV: 16 t-rows x 256 d-cols, K = 64 (2 chunks), V from LDS
#pragma unroll
    for (int kc = 0; kc < 2; ++kc) {
      half8 pa = *(const half8*)(pw + l15 * 72 + kc * 32 + q * 8);
      __builtin_amdgcn_s_setprio(1);
#pragma unroll
      for (int dt = 0; dt < 16; ++dt) {
        half8 vb = *(const half8*)(vt + (dt * 16 + l15) * 72 + kc * 32 + q * 8);
        acc[dt] = mfma16(pa, vb, acc[dt]);
      }
      __builtin_amdgcn_s_setprio(0);
    }
  }
  float inv[4];
#pragma unroll
  for (int r = 0; r < 4; ++r) inv[r] = 1.0f / lr[r];
#pragma unroll
  for (int dt = 0; dt < 16; ++dt)
#pragma unroll
    for (int r = 0; r < 4; ++r) {
      int t = t0 + 16 * wv + q * 4 + r;
      if (t < 2000) {
        int d = dt * 16 + l15;
        out[((size_t)b * 2000 + t) * 512 + 256 + d] = acc[dt][r] * inv[r];
      }
    }
}

extern "C" void kernel_launch(void* const* d_in, const int* in_sizes, int n_in,
                              void* d_out, int out_size, void* d_ws, size_t ws_size,
                              hipStream_t stream) {
  (void)in_sizes; (void)n_in; (void)out_size; (void)ws_size;
  const float* mels       = (const float*)d_in[0];
  const int*   phonemes   = (const int*)d_in[1];
  const int*   mel_lens   = (const int*)d_in[2];
  const int*   ph_lens    = (const int*)d_in[3];
  const float* embedding  = (const float*)d_in[4];
  const float* mel_conv_w = (const float*)d_in[5];
  const float* mel_conv_b = (const float*)d_in[6];
  const float* ph_w       = (const float*)d_in[7];
  const float* ph_b       = (const float*)d_in[8];
  const float* mel_w      = (const float*)d_in[9];
  const float* mel_b      = (const float*)d_in[10];
  float* out = (float*)d_out;

  char* wsp = (char*)d_ws;
  size_t off = 0;
  auto alloc = [&](size_t bytes) -> void* {
    void* p = wsp + off;
    off = (off + bytes + 255) & ~(size_t)255;
    return p;
  };
  // NOTE: p0 must NOT be the last allocation — flash reads up to 63 rows past
  // its end (masked columns). p1/m0 follow it -> in-workspace, safe. GLU also
  // reads 1 row before/after its x buffer (taps) -> in-workspace, masked.
  // p1 is a REAL buffer (not aliased to m1): fused GLU runs mel and ph
  // layers concurrently, so m1 is live while the ph ping buffer is written.
  // phT still aliases m1 (transpose runs after the last fused layer, whose
  // mel output is m0).
  f16* wtg    = (f16*)alloc(8ull * 4 * 12 * 8192 * 2);  // frag-ordered GLU W
  f16* wt0    = (f16*)alloc(256ull * 288 * 2);
  float* phsq = (float*)alloc(16416ull * 4);
  f16* p0     = (f16*)alloc(32ull * 513 * 256 * 2);
  f16* p1     = (f16*)alloc(32ull * 513 * 256 * 2);
  f16* m0     = (f16*)alloc(32ull * 2000 * 256 * 2);
  f16* m1     = (f16*)alloc(32ull * 2000 * 256 * 2);
  f16* phT = m1;        // 9.4 MB <= 32.8 MB, used after GLUs done

  prep_wtglu_kernel<<<384, 256, 0, stream>>>(mel_w, ph_w, wtg);
  prep_wt0_kernel<<<288, 256, 0, stream>>>(mel_conv_w, wt0);
  embed_kernel<<<dim3(513, 32), 64, 0, stream>>>(phonemes, embedding, p0);
  conv0_kernel<<<dim3(32, 4, 32), 256, 0, stream>>>(mels, wt0, mel_conv_b, m0);

  const size_t WL = 4ull * 12 * 8192;  // f16 per GLU layer
  // fused GLU layers: mel layer i (mask: t >= mel_lens[b]) + ph layer i
  // (mask: s > phoneme_lens[b]) in one dispatch; ph blocks backfill the tail.
  // Only the last layer writes the masked-region constant.
  glu_fused_kernel<<<2688, 256, 0, stream>>>(
      m0, wtg + 0 * WL, mel_b + 0 * 512, m1, mel_lens,
      p0, wtg + 4 * WL, ph_b + 0 * 512, p1, ph_lens, 0);
  glu_fused_kernel<<<2688, 256, 0, stream>>>(
      m1, wtg + 1 * WL, mel_b + 1 * 512, m0, mel_lens,
      p1, wtg + 5 * WL, ph_b + 1 * 512, p0, ph_lens, 0);
  glu_fused_kernel<<<2688, 256, 0, stream>>>(
      m0, wtg + 2 * WL, mel_b + 2 * 512, m1, mel_lens,
      p0, wtg + 6 * WL, ph_b + 2 * 512, p1, ph_lens, 0);
  glu_fused_kernel<<<2688, 256, 0, stream>>>(
      m1, wtg + 3 * WL, mel_b + 3 * 512, m0, mel_lens,
      p1, wtg + 7 * WL, ph_b + 3 * 512, p0, ph_lens, 1);

  transpose_kernel<<<dim3(9, 4, 32), 256, 0, stream>>>(p0, phT);
  sqnorm_kernel<<<4104, 256, 0, stream>>>(p0, phsq, 16416);
  flash_kernel<<<dim3(32 * 32), 256, 0, stream>>>(m0, p0, phT, phsq, ph_lens, out);
}